// Round 5
// baseline (663.839 us; speedup 1.0000x reference)
//
#include <hip/hip_runtime.h>
#include <hip/hip_bf16.h>

typedef __hip_bfloat16 bf16;
typedef __bf16 bf16x8 __attribute__((ext_vector_type(8)));
typedef float f32x4 __attribute__((ext_vector_type(4)));

#define BAG 8
#define SEQ 512
#define DM 768
#define NPD 6
#define NNODE 48
#define TT 2304
#define NH 8
#define DKH 96
#define DFF 1024
#define NLAYER 4
#define NREL 97
#define SP 6
#define KSPAN (TT / SP)
#define LN_EPS 1e-5f

__device__ __forceinline__ float b2f(const bf16 x) { return __bfloat162float(x); }
__device__ __forceinline__ bf16 f2b(float f) { return __float2bfloat16(f); }
__device__ __forceinline__ unsigned short f2bu(float f) {
    bf16 h = __float2bfloat16(f);
    return *reinterpret_cast<unsigned short*>(&h);
}

// XCD-aware bijective block remap: contiguous row-major chunks per XCD.
// Requires gridDim.x*gridDim.y % 8 == 0 (all our launches satisfy this).
__device__ __forceinline__ void xcd_swizzle(int& bx, int& by) {
    const int gx = gridDim.x;
    const int id = blockIdx.y * gx + blockIdx.x;
    const int per = (gx * gridDim.y) >> 3;
    const int lin = (id & 7) * per + (id >> 3);
    by = lin / gx;
    bx = lin - by * gx;
}

__global__ __launch_bounds__(128) void span_pool(const float* __restrict__ emb,
                                                 const int* __restrict__ spans,
                                                 bf16* __restrict__ htb) {
    const int n = blockIdx.x;
    const int b = n / NPD;
    int s0 = spans[n * 2 + 0];
    int s1 = spans[n * 2 + 1];
    s0 = min(max(s0, 0), SEQ - 1);
    s1 = min(max(s1, s0), SEQ - 1);
    const float* base = emb + (size_t)b * SEQ * DM;
    const int d = blockIdx.y * 128 + threadIdx.x;
    float m = -3.0e38f;
    for (int s = s0; s <= s1; ++s) m = fmaxf(m, base[(size_t)s * DM + d]);
    htb[(size_t)n * DM + d] = f2b(m);
}

// ---------------------------------------------------------------------------
// weight prep (3 DMxDM): W[K][N] f32 -> Wt[N][K] bf16, out at z*DM*DM
// ---------------------------------------------------------------------------
__global__ __launch_bounds__(256) void prep_wt3(const float* __restrict__ W0,
                                                const float* __restrict__ W1,
                                                const float* __restrict__ W2,
                                                bf16* __restrict__ Wt) {
    __shared__ __align__(16) __bf16 tile[64][72];
    const int z = blockIdx.z;
    const float* W = (z == 0) ? W0 : (z == 1) ? W1 : W2;
    bf16* out = Wt + (size_t)z * DM * DM;
    const int t = threadIdx.x;
    const int k0 = blockIdx.x * 64, n0 = blockIdx.y * 64;
    const int r = t >> 2, cg = (t & 3) * 16;
#pragma unroll
    for (int i = 0; i < 4; ++i) {
        const float4 v = *(const float4*)&W[(size_t)(k0 + r) * DM + n0 + cg + 4 * i];
        tile[r][cg + 4 * i + 0] = (__bf16)v.x;
        tile[r][cg + 4 * i + 1] = (__bf16)v.y;
        tile[r][cg + 4 * i + 2] = (__bf16)v.z;
        tile[r][cg + 4 * i + 3] = (__bf16)v.w;
    }
    __syncthreads();
#pragma unroll
    for (int i = 0; i < 2; ++i) {
        bf16x8 o;
#pragma unroll
        for (int j = 0; j < 8; ++j) o[j] = tile[cg + 8 * i + j][r];
        *(bf16x8*)&out[(size_t)(n0 + r) * DM + k0 + cg + 8 * i] = o;
    }
}

// ---------------------------------------------------------------------------
// prep6: one launch converts Wq,Wk,Wv,Wo,F1,F2 -> transposed bf16 slab.
// ---------------------------------------------------------------------------
__global__ __launch_bounds__(256) void prep6(const float* __restrict__ Wq,
                                             const float* __restrict__ Wk,
                                             const float* __restrict__ Wv,
                                             const float* __restrict__ Wo,
                                             const float* __restrict__ F1,
                                             const float* __restrict__ F2,
                                             bf16* __restrict__ slab) {
    __shared__ __align__(16) __bf16 tile[64][72];
    const int z = blockIdx.z;
    int K = DM, N = DM;
    const float* W;
    size_t off;
    switch (z) {
        case 0: W = Wq; off = 0;       break;
        case 1: W = Wk; off = 589824;  break;
        case 2: W = Wv; off = 1179648; break;
        case 3: W = Wo; off = 1769472; break;
        case 4: W = F1; off = 2359296; N = DFF; break;
        default: W = F2; off = 3145728; K = DFF; break;
    }
    const int k0 = blockIdx.x * 64, n0 = blockIdx.y * 64;
    if (k0 >= K || n0 >= N) return;
    bf16* out = slab + off;
    const int t = threadIdx.x;
    const int r = t >> 2, cg = (t & 3) * 16;
#pragma unroll
    for (int i = 0; i < 4; ++i) {
        const float4 v = *(const float4*)&W[(size_t)(k0 + r) * N + n0 + cg + 4 * i];
        tile[r][cg + 4 * i + 0] = (__bf16)v.x;
        tile[r][cg + 4 * i + 1] = (__bf16)v.y;
        tile[r][cg + 4 * i + 2] = (__bf16)v.z;
        tile[r][cg + 4 * i + 3] = (__bf16)v.w;
    }
    __syncthreads();
#pragma unroll
    for (int i = 0; i < 2; ++i) {
        bf16x8 o;
#pragma unroll
        for (int j = 0; j < 8; ++j) o[j] = tile[cg + 8 * i + j][r];
        *(bf16x8*)&out[(size_t)(n0 + r) * K + k0 + cg + 8 * i] = o;
    }
}

// ---------------------------------------------------------------------------
// MFMA GEMM: 64x64 tile, 256 threads = 4 waves 2x2, BK=64, double-buffered,
// one barrier per K-iter, XCD-swizzled grid.
// DUAL=1: bias split [bias|bias2] at col DM.  RESID=1: C = acc + bias + R.
// ---------------------------------------------------------------------------
template <int RELU, int DUAL, int RESID>
__global__ __launch_bounds__(256) void gemm_bt256(const bf16* __restrict__ A,
                                                  const bf16* __restrict__ Bt,
                                                  const float* __restrict__ bias,
                                                  const float* __restrict__ bias2,
                                                  const bf16* __restrict__ R,
                                                  bf16* __restrict__ C,
                                                  int M, int N, int K) {
    __shared__ __align__(16) __bf16 As[2][64][72];
    __shared__ __align__(16) __bf16 Bs[2][64][72];
    const int t = threadIdx.x;
    const int w = t >> 6, lane = t & 63;
    const int quad = lane >> 4, l15 = lane & 15;
    const int wr = w >> 1, wc = w & 1;            // 2x2 wave grid
    int bx, by;
    xcd_swizzle(bx, by);
    const int row0 = by * 64, col0 = bx * 64;
    const int s_row = t >> 2, s_off = (t & 3) * 16;
    const bool a_ok = (row0 + s_row) < M;

    const f32x4 fz = {0.f, 0.f, 0.f, 0.f};
    f32x4 acc[2][2];
#pragma unroll
    for (int m = 0; m < 2; ++m)
#pragma unroll
        for (int n = 0; n < 2; ++n) acc[m][n] = fz;

    bf16x8 av[2], bv[2];
#pragma unroll
    for (int j = 0; j < 2; ++j)
#pragma unroll
        for (int e = 0; e < 8; ++e) av[j][e] = (__bf16)0.0f;
    if (a_ok)
#pragma unroll
        for (int j = 0; j < 2; ++j)
            av[j] = *(const bf16x8*)&A[(size_t)(row0 + s_row) * K + s_off + 8 * j];
#pragma unroll
    for (int j = 0; j < 2; ++j)
        bv[j] = *(const bf16x8*)&Bt[(size_t)(col0 + s_row) * K + s_off + 8 * j];

    int cur = 0;
    for (int k0 = 0; k0 < K; k0 += 64) {
#pragma unroll
        for (int j = 0; j < 2; ++j) {
            *(bf16x8*)&As[cur][s_row][s_off + 8 * j] = av[j];
            *(bf16x8*)&Bs[cur][s_row][s_off + 8 * j] = bv[j];
        }
        __syncthreads();

        if (k0 + 64 < K) {
            if (a_ok)
#pragma unroll
                for (int j = 0; j < 2; ++j)
                    av[j] = *(const bf16x8*)&A[(size_t)(row0 + s_row) * K + k0 + 64 + s_off + 8 * j];
#pragma unroll
            for (int j = 0; j < 2; ++j)
                bv[j] = *(const bf16x8*)&Bt[(size_t)(col0 + s_row) * K + k0 + 64 + s_off + 8 * j];
        }

#pragma unroll
        for (int kk = 0; kk < 2; ++kk) {
            const bf16x8 af0 = *(const bf16x8*)&As[cur][wr * 32 + l15][quad * 8 + 32 * kk];
            const bf16x8 af1 = *(const bf16x8*)&As[cur][wr * 32 + 16 + l15][quad * 8 + 32 * kk];
            const bf16x8 bf0 = *(const bf16x8*)&Bs[cur][wc * 32 + l15][quad * 8 + 32 * kk];
            const bf16x8 bf1 = *(const bf16x8*)&Bs[cur][wc * 32 + 16 + l15][quad * 8 + 32 * kk];
            acc[0][0] = __builtin_amdgcn_mfma_f32_16x16x32_bf16(af0, bf0, acc[0][0], 0, 0, 0);
            acc[0][1] = __builtin_amdgcn_mfma_f32_16x16x32_bf16(af0, bf1, acc[0][1], 0, 0, 0);
            acc[1][0] = __builtin_amdgcn_mfma_f32_16x16x32_bf16(af1, bf0, acc[1][0], 0, 0, 0);
            acc[1][1] = __builtin_amdgcn_mfma_f32_16x16x32_bf16(af1, bf1, acc[1][1], 0, 0, 0);
        }
        cur ^= 1;
    }

#pragma unroll
    for (int n = 0; n < 2; ++n) {
        const int col = col0 + wc * 32 + 16 * n + l15;
        const float bvl = (DUAL && col >= DM) ? bias2[col - DM] : bias[col];
#pragma unroll
        for (int m = 0; m < 2; ++m)
#pragma unroll
            for (int r = 0; r < 4; ++r) {
                const int row = row0 + wr * 32 + 16 * m + quad * 4 + r;
                if (row < M) {
                    float v = acc[m][n][r] + bvl;
                    if (RESID) v += b2f(R[(size_t)row * N + col]);
                    if (RELU) v = fmaxf(v, 0.f);
                    C[(size_t)row * N + col] = f2b(v);
                }
            }
    }
}

// ---------------------------------------------------------------------------
// gemm_rel: rel GEMM with build_relA FUSED into A-staging, XCD-swizzled.
// ---------------------------------------------------------------------------
__global__ __launch_bounds__(256) void gemm_rel(const bf16* __restrict__ u2,
                                                const bf16* __restrict__ Bt,
                                                const float* __restrict__ bias,
                                                bf16* __restrict__ C) {
    __shared__ __align__(16) __bf16 As[2][64][72];
    __shared__ __align__(16) __bf16 Bs[2][64][72];
    const int t = threadIdx.x;
    const int w = t >> 6, lane = t & 63;
    const int quad = lane >> 4, l15 = lane & 15;
    const int wr = w >> 1, wc = w & 1;
    int bx, by;
    xcd_swizzle(bx, by);
    const int row0 = by * 64, col0 = bx * 64;
    const int s_row = t >> 2, s_off = (t & 3) * 16;
    const int cell = row0 + s_row;
    const bf16* up = u2 + (size_t)(cell / NNODE) * (2 * DM);
    const bf16* vp = u2 + (size_t)(cell % NNODE) * (2 * DM) + DM;

    const f32x4 fz = {0.f, 0.f, 0.f, 0.f};
    f32x4 acc[2][2];
#pragma unroll
    for (int m = 0; m < 2; ++m)
#pragma unroll
        for (int n = 0; n < 2; ++n) acc[m][n] = fz;

    bf16x8 uu[2], vv[2], bv[2];
#pragma unroll
    for (int j = 0; j < 2; ++j) {
        uu[j] = *(const bf16x8*)&up[s_off + 8 * j];
        vv[j] = *(const bf16x8*)&vp[s_off + 8 * j];
        bv[j] = *(const bf16x8*)&Bt[(size_t)(col0 + s_row) * DM + s_off + 8 * j];
    }

    int cur = 0;
    for (int k0 = 0; k0 < DM; k0 += 64) {
#pragma unroll
        for (int j = 0; j < 2; ++j) {
            bf16x8 o;
#pragma unroll
            for (int e = 0; e < 8; ++e)
                o[e] = (__bf16)fmaxf((float)uu[j][e] + (float)vv[j][e], 0.f);
            *(bf16x8*)&As[cur][s_row][s_off + 8 * j] = o;
            *(bf16x8*)&Bs[cur][s_row][s_off + 8 * j] = bv[j];
        }
        __syncthreads();

        if (k0 + 64 < DM) {
#pragma unroll
            for (int j = 0; j < 2; ++j) {
                uu[j] = *(const bf16x8*)&up[k0 + 64 + s_off + 8 * j];
                vv[j] = *(const bf16x8*)&vp[k0 + 64 + s_off + 8 * j];
                bv[j] = *(const bf16x8*)&Bt[(size_t)(col0 + s_row) * DM + k0 + 64 + s_off + 8 * j];
            }
        }

#pragma unroll
        for (int kk = 0; kk < 2; ++kk) {
            const bf16x8 af0 = *(const bf16x8*)&As[cur][wr * 32 + l15][quad * 8 + 32 * kk];
            const bf16x8 af1 = *(const bf16x8*)&As[cur][wr * 32 + 16 + l15][quad * 8 + 32 * kk];
            const bf16x8 bf0 = *(const bf16x8*)&Bs[cur][wc * 32 + l15][quad * 8 + 32 * kk];
            const bf16x8 bf1 = *(const bf16x8*)&Bs[cur][wc * 32 + 16 + l15][quad * 8 + 32 * kk];
            acc[0][0] = __builtin_amdgcn_mfma_f32_16x16x32_bf16(af0, bf0, acc[0][0], 0, 0, 0);
            acc[0][1] = __builtin_amdgcn_mfma_f32_16x16x32_bf16(af0, bf1, acc[0][1], 0, 0, 0);
            acc[1][0] = __builtin_amdgcn_mfma_f32_16x16x32_bf16(af1, bf0, acc[1][0], 0, 0, 0);
            acc[1][1] = __builtin_amdgcn_mfma_f32_16x16x32_bf16(af1, bf1, acc[1][1], 0, 0, 0);
        }
        cur ^= 1;
    }

#pragma unroll
    for (int n = 0; n < 2; ++n) {
        const int col = col0 + wc * 32 + 16 * n + l15;
        const float bvl = bias[col];
#pragma unroll
        for (int m = 0; m < 2; ++m)
#pragma unroll
            for (int r = 0; r < 4; ++r) {
                const int row = row0 + wr * 32 + 16 * m + quad * 4 + r;
                C[(size_t)row * DM + col] = f2b(fmaxf(acc[m][n][r] + bvl, 0.f));
            }
    }
}

// ---------------------------------------------------------------------------
// fused QKV GEMM: 64x64 tile, 256 threads, double-buffered, XCD-swizzled.
// V tiles (col0 >= 2*DM) written TRANSPOSED to Vt[768][TT] via LDS bounce.
// ---------------------------------------------------------------------------
__global__ __launch_bounds__(256) void gemm_qkv256(const bf16* __restrict__ A,
                                                   const bf16* __restrict__ Bt,
                                                   const float* __restrict__ b0,
                                                   const float* __restrict__ b1,
                                                   const float* __restrict__ b2,
                                                   bf16* __restrict__ C0,
                                                   bf16* __restrict__ C1,
                                                   bf16* __restrict__ Vt) {
    __shared__ __align__(16) __bf16 As[2][64][72];
    __shared__ __align__(16) __bf16 Bs[2][64][72];
    const int t = threadIdx.x;
    const int w = t >> 6, lane = t & 63;
    const int quad = lane >> 4, l15 = lane & 15;
    const int wr = w >> 1, wc = w & 1;
    int bx, by;
    xcd_swizzle(bx, by);
    const int row0 = by * 64, col0 = bx * 64;
    const int s_row = t >> 2, s_off = (t & 3) * 16;

    const f32x4 fz = {0.f, 0.f, 0.f, 0.f};
    f32x4 acc[2][2];
#pragma unroll
    for (int m = 0; m < 2; ++m)
#pragma unroll
        for (int n = 0; n < 2; ++n) acc[m][n] = fz;

    bf16x8 av[2], bv[2];
#pragma unroll
    for (int j = 0; j < 2; ++j) {
        av[j] = *(const bf16x8*)&A[(size_t)(row0 + s_row) * DM + s_off + 8 * j];
        bv[j] = *(const bf16x8*)&Bt[(size_t)(col0 + s_row) * DM + s_off + 8 * j];
    }

    int cur = 0;
    for (int k0 = 0; k0 < DM; k0 += 64) {
#pragma unroll
        for (int j = 0; j < 2; ++j) {
            *(bf16x8*)&As[cur][s_row][s_off + 8 * j] = av[j];
            *(bf16x8*)&Bs[cur][s_row][s_off + 8 * j] = bv[j];
        }
        __syncthreads();

        if (k0 + 64 < DM) {
#pragma unroll
            for (int j = 0; j < 2; ++j) {
                av[j] = *(const bf16x8*)&A[(size_t)(row0 + s_row) * DM + k0 + 64 + s_off + 8 * j];
                bv[j] = *(const bf16x8*)&Bt[(size_t)(col0 + s_row) * DM + k0 + 64 + s_off + 8 * j];
            }
        }

#pragma unroll
        for (int kk = 0; kk < 2; ++kk) {
            const bf16x8 af0 = *(const bf16x8*)&As[cur][wr * 32 + l15][quad * 8 + 32 * kk];
            const bf16x8 af1 = *(const bf16x8*)&As[cur][wr * 32 + 16 + l15][quad * 8 + 32 * kk];
            const bf16x8 bf0 = *(const bf16x8*)&Bs[cur][wc * 32 + l15][quad * 8 + 32 * kk];
            const bf16x8 bf1 = *(const bf16x8*)&Bs[cur][wc * 32 + 16 + l15][quad * 8 + 32 * kk];
            acc[0][0] = __builtin_amdgcn_mfma_f32_16x16x32_bf16(af0, bf0, acc[0][0], 0, 0, 0);
            acc[0][1] = __builtin_amdgcn_mfma_f32_16x16x32_bf16(af0, bf1, acc[0][1], 0, 0, 0);
            acc[1][0] = __builtin_amdgcn_mfma_f32_16x16x32_bf16(af1, bf0, acc[1][0], 0, 0, 0);
            acc[1][1] = __builtin_amdgcn_mfma_f32_16x16x32_bf16(af1, bf1, acc[1][1], 0, 0, 0);
        }
        cur ^= 1;
    }

    const int buf = col0 / DM;
    const int lc0 = col0 - buf * DM;
    if (buf < 2) {
        bf16* Cb = (buf == 0) ? C0 : C1;
        const float* bb = (buf == 0) ? b0 : b1;
#pragma unroll
        for (int n = 0; n < 2; ++n) {
            const int col = lc0 + wc * 32 + 16 * n + l15;
            const float bvl = bb[col];
#pragma unroll
            for (int m = 0; m < 2; ++m)
#pragma unroll
                for (int r = 0; r < 4; ++r) {
                    const int row = row0 + wr * 32 + 16 * m + quad * 4 + r;
                    Cb[(size_t)row * DM + col] = f2b(acc[m][n][r] + bvl);
                }
        }
    } else {
        __bf16 (*Tb)[72] = As[0];   // [col_local][row_local]
        __syncthreads();
#pragma unroll
        for (int n = 0; n < 2; ++n) {
            const int cl = wc * 32 + 16 * n + l15;
            const float bvl = b2[lc0 + cl];
#pragma unroll
            for (int m = 0; m < 2; ++m)
#pragma unroll
                for (int r = 0; r < 4; ++r)
                    Tb[cl][wr * 32 + 16 * m + quad * 4 + r] = (__bf16)(acc[m][n][r] + bvl);
        }
        __syncthreads();
        const int c = t >> 2, seg = (t & 3) * 16;
        const bf16x8 o0 = *(const bf16x8*)&Tb[c][seg];
        const bf16x8 o1 = *(const bf16x8*)&Tb[c][seg + 8];
        *(bf16x8*)&Vt[(size_t)(lc0 + c) * TT + row0 + seg] = o0;
        *(bf16x8*)&Vt[(size_t)(lc0 + c) * TT + row0 + seg + 8] = o1;
    }
}

// fallback GEMM (f32 weights, staging conversion)
template <int RELU>
__global__ __launch_bounds__(128) void gemm_mfma(const bf16* __restrict__ A,
                                                 const float* __restrict__ W,
                                                 const float* __restrict__ bias,
                                                 bf16* __restrict__ C,
                                                 int M, int N, int K) {
    __shared__ __align__(16) __bf16 As[32][40];
    __shared__ __align__(16) __bf16 Bs[64][40];
    const int t = threadIdx.x;
    const int w = t >> 6, lane = t & 63;
    const int quad = lane >> 4, l15 = lane & 15;
    const int row0 = blockIdx.y * 32, col0 = blockIdx.x * 64;
    const int s_row = t >> 2, s_kg = (t & 3) * 8;
    const int s_colg = (t & 15) * 4, s_kp = t >> 4;
    const bool a_ok = (row0 + s_row) < M;
    const f32x4 fz = {0.f, 0.f, 0.f, 0.f};
    f32x4 acc[4];
#pragma unroll
    for (int i = 0; i < 4; ++i) acc[i] = fz;

    for (int k0 = 0; k0 < K; k0 += 32) {
        bf16x8 av;
        for (int j = 0; j < 8; ++j) av[j] = (__bf16)0.0f;
        if (a_ok) av = *(const bf16x8*)&A[(size_t)(row0 + s_row) * K + k0 + s_kg];
        *(bf16x8*)&As[s_row][s_kg] = av;
#pragma unroll
        for (int rep = 0; rep < 2; ++rep) {
            const int kp = s_kp + 8 * rep;
            const size_t gb = (size_t)(k0 + 2 * kp) * N + col0 + s_colg;
            const float4 w0 = *(const float4*)&W[gb];
            const float4 w1 = *(const float4*)&W[gb + N];
#pragma unroll
            for (int i = 0; i < 4; ++i) {
                ushort2 pk;
                pk.x = f2bu((&w0.x)[i]);
                pk.y = f2bu((&w1.x)[i]);
                *(ushort2*)&Bs[s_colg + i][2 * kp] = pk;
            }
        }
        __syncthreads();
        const bf16x8 af = *(const bf16x8*)&As[16 * w + l15][quad * 8];
#pragma unroll
        for (int nt = 0; nt < 4; ++nt) {
            const bf16x8 bfv = *(const bf16x8*)&Bs[16 * nt + l15][quad * 8];
            acc[nt] = __builtin_amdgcn_mfma_f32_16x16x32_bf16(af, bfv, acc[nt], 0, 0, 0);
        }
        __syncthreads();
    }
#pragma unroll
    for (int nt = 0; nt < 4; ++nt) {
        const int col = col0 + 16 * nt + l15;
        const float bvl = bias[col];
#pragma unroll
        for (int r = 0; r < 4; ++r) {
            const int row = row0 + 16 * w + quad * 4 + r;
            if (row < M) {
                float v = acc[nt][r] + bvl;
                if (RELU) v = fmaxf(v, 0.f);
                C[(size_t)row * N + col] = f2b(v);
            }
        }
    }
}

// build_relA (fallback path only)
__global__ __launch_bounds__(256) void build_relA(const bf16* __restrict__ u,
                                                  const bf16* __restrict__ v,
                                                  int stride,
                                                  bf16* __restrict__ A) {
    const int cell = blockIdx.x;
    const int i = cell / NNODE, j = cell % NNODE;
    for (int k = threadIdx.x; k < DM; k += 256) {
        A[(size_t)cell * DM + k] =
            f2b(fmaxf(b2f(u[(size_t)i * stride + k]) + b2f(v[(size_t)j * stride + k]), 0.f));
    }
}

__global__ __launch_bounds__(256) void transpose_v(const bf16* __restrict__ v,
                                                   bf16* __restrict__ vt) {
    __shared__ __align__(16) __bf16 tile[64][72];
    const int t = threadIdx.x;
    const int bx = blockIdx.x, by = blockIdx.y;
    const int r = t >> 2, cg = (t & 3) * 16;
#pragma unroll
    for (int i = 0; i < 2; ++i)
        *(bf16x8*)&tile[r][cg + 8 * i] =
            *(const bf16x8*)&v[(size_t)(by * 64 + r) * DM + bx * 64 + cg + 8 * i];
    __syncthreads();
#pragma unroll
    for (int i = 0; i < 2; ++i) {
        bf16x8 o;
#pragma unroll
        for (int j = 0; j < 8; ++j) o[j] = tile[cg + 8 * i + j][r];
        *(bf16x8*)&vt[(size_t)(bx * 64 + r) * TT + by * 64 + cg + 8 * i] = o;
    }
}

// ---------------------------------------------------------------------------
// MFMA flash attention (round-4 proven): XCD swizzle, exp2 folded scale,
// MFMA ones-row row-sum.  LDS = 38656 B -> 4 blocks/CU.
// ---------------------------------------------------------------------------
template <int MODE>   // 0 direct, 1 bf16 partials
__global__ __launch_bounds__(256) void attn_mfma(const bf16* __restrict__ qb,
                                                 const bf16* __restrict__ kb,
                                                 const bf16* __restrict__ vtb,
                                                 bf16* __restrict__ ob,
                                                 bf16* __restrict__ Opb,
                                                 float* __restrict__ Lp,
                                                 int kspan) {
    __shared__ __align__(16) __bf16 Ks[64][104];    // 13312 B
    __shared__ __align__(16) __bf16 Vts[112][72];   // 16128 B (row 96 = ones)
    __shared__ __align__(16) __bf16 Ps[4][16][72];  //  9216 B

    const int t = threadIdx.x;
    const int w = t >> 6, lane = t & 63;
    const int quad = lane >> 4, l15 = lane & 15;

    const int lid = blockIdx.x;
    const int xcd = lid & 7;
    const int s = lid >> 3;
    const int per = gridDim.x / 288;            // combos per XCD
    const int combo = xcd * per + s / 36;
    const int h = combo % NH;
    const int p = combo / NH;
    const int q0 = (s % 36) * 64;
    const int kstart = p * kspan;
    const float scale = 0.10206207261596575f * 1.4426950408889634f;  // /sqrt(96)*log2e

    bf16x8 qf[3];
#pragma unroll
    for (int ks = 0; ks < 3; ++ks) {
        qf[ks] = *(const bf16x8*)&qb[(size_t)(q0 + 16 * w + l15) * DM + h * DKH + quad * 8 + 32 * ks];
#pragma unroll
        for (int j = 0; j < 8; ++j) qf[ks][j] = (__bf16)((float)qf[ks][j] * scale);
    }

    const f32x4 fz = {0.f, 0.f, 0.f, 0.f};
    f32x4 Oa[6];
#pragma unroll
    for (int i = 0; i < 6; ++i) Oa[i] = fz;
    f32x4 Lacc = fz;
    float lrow[4] = {0.f, 0.f, 0.f, 0.f};

    if (MODE == 1 && t < 8) {
        bf16x8 one;
#pragma unroll
        for (int e = 0; e < 8; ++e) one[e] = (__bf16)1.0f;
        *(bf16x8*)&Vts[96][t * 8] = one;
    }

    bf16x8 kreg[3], vreg[3];
#pragma unroll
    for (int i = 0; i < 3; ++i) {
        const int idx = t + 256 * i;
        const int r = idx / 12, c = idx % 12;
        kreg[i] = *(const bf16x8*)&kb[(size_t)(kstart + r) * DM + h * DKH + c * 8];
        const int d = idx >> 3, ck = idx & 7;
        vreg[i] = *(const bf16x8*)&vtb[(size_t)(h * DKH + d) * TT + kstart + ck * 8];
    }

    for (int kc = kstart; kc < kstart + kspan; kc += 64) {
        __syncthreads();
#pragma unroll
        for (int i = 0; i < 3; ++i) {
            const int idx = t + 256 * i;
            const int r = idx / 12, c = idx % 12;
            *(bf16x8*)&Ks[r][c * 8] = kreg[i];
            const int d = idx >> 3, ck = idx & 7;
            *(bf16x8*)&Vts[d][ck * 8] = vreg[i];
        }
        __syncthreads();

        if (kc + 64 < kstart + kspan) {
#pragma unroll
            for (int i = 0; i < 3; ++i) {
                const int idx = t + 256 * i;
                const int r = idx / 12, c = idx % 12;
                kreg[i] = *(const bf16x8*)&kb[(size_t)(kc + 64 + r) * DM + h * DKH + c * 8];
                const int d = idx >> 3, ck = idx & 7;
                vreg[i] = *(const bf16x8*)&vtb[(size_t)(h * DKH + d) * TT + kc + 64 + ck * 8];
            }
        }

        f32x4 Sa[4] = {fz, fz, fz, fz};
#pragma unroll
        for (int nt = 0; nt < 4; ++nt)
#pragma unroll
            for (int ks = 0; ks < 3; ++ks) {
                const bf16x8 kf = *(const bf16x8*)&Ks[l15 + 16 * nt][quad * 8 + 32 * ks];
                Sa[nt] = __builtin_amdgcn_mfma_f32_16x16x32_bf16(qf[ks], kf, Sa[nt], 0, 0, 0);
            }

#pragma unroll
        for (int r = 0; r < 4; ++r) {
            const float p0 = __builtin_amdgcn_exp2f(Sa[0][r]);
            const float p1 = __builtin_amdgcn_exp2f(Sa[1][r]);
            const float p2 = __builtin_amdgcn_exp2f(Sa[2][r]);
            const float p3 = __builtin_amdgcn_exp2f(Sa[3][r]);
            Ps[w][quad * 4 + r][l15]      = (__bf16)p0;
            Ps[w][quad * 4 + r][l15 + 16] = (__bf16)p1;
            Ps[w][quad * 4 + r][l15 + 32] = (__bf16)p2;
            Ps[w][quad * 4 + r][l15 + 48] = (__bf16)p3;
            if (MODE == 0) {
                float ps = p0 + p1 + p2 + p3;
                ps += __shfl_xor(ps, 1);
                ps += __shfl_xor(ps, 2);
                ps += __shfl_xor(ps, 4);
                ps += __shfl_xor(ps, 8);
                lrow[r] += ps;
            }
        }

        const bf16x8 pa0 = *(const bf16x8*)&Ps[w][l15][quad * 8];
        const bf16x8 pa1 = *(const bf16x8*)&Ps[w][l15][32 + quad * 8];

#pragma unroll
        for (int nt = 0; nt < 6; ++nt) {
            const bf16x8 vf0 = *(const bf16x8*)&Vts[l15 + 16 * nt][quad * 8];
            const bf16x8 vf1 = *(const bf16x8*)&Vts[l15 + 16 * nt][32 + quad * 8];
            Oa[nt] = __builtin_amdgcn_mfma_f32_16x16x32_bf16(pa0, vf0, Oa[nt], 0, 0, 0);
            Oa[nt] = __builtin_amdgcn_mfma_f32_16x16x32_bf16(pa1, vf1, Oa[nt], 0, 0, 0);
        }
        if (MODE == 1) {
            const bf16x8 of0 = *(const bf16x8*)&Vts[96 + l15][quad * 8];
            const bf16x8 of1 = *(const bf16x8*)&Vts[96 + l15][32 + quad * 8];
            Lacc = __builtin_amdgcn_mfma_f32_16x16x32_bf16(pa0, of0, Lacc, 0, 0, 0);
            Lacc = __builtin_amdgcn_mfma_f32_16x16x32_bf16(pa1, of1, Lacc, 0, 0, 0);
        }
    }

    if (MODE == 0) {
#pragma unroll
        for (int nt = 0; nt < 6; ++nt)
#pragma unroll
            for (int r = 0; r < 4; ++r) {
                const int row = q0 + 16 * w + quad * 4 + r;
                ob[(size_t)row * DM + h * DKH + 16 * nt + l15] = f2b(Oa[nt][r] / lrow[r]);
            }
    } else {
#pragma unroll
        for (int nt = 0; nt < 6; ++nt)
#pragma unroll
            for (int r = 0; r < 4; ++r) {
                const int row = q0 + 16 * w + quad * 4 + r;
                Opb[((size_t)p * TT + row) * DM + h * DKH + 16 * nt + l15] = f2b(Oa[nt][r]);
            }
        if (l15 == 0) {
#pragma unroll
            for (int r = 0; r < 4; ++r) {
                const int row = q0 + 16 * w + quad * 4 + r;
                Lp[((size_t)p * NH + h) * TT + row] = Lacc[r];
            }
        }
    }
}

// ---------------------------------------------------------------------------
// merge: 8 rows/block, bf16x8 vector loads.
// ---------------------------------------------------------------------------
__global__ __launch_bounds__(256) void attn_merge(const bf16* __restrict__ Opb,
                                                  const float* __restrict__ Lp,
                                                  bf16* __restrict__ ob) {
    __shared__ float Ls[8][NH];
    const int r0 = blockIdx.x * 8;
    const int t = threadIdx.x;
    if (t < 8 * NH) {
        const int rl = t >> 3, hh = t & 7;
        float L = 0.f;
#pragma unroll
        for (int p = 0; p < SP; ++p) L += Lp[((size_t)p * NH + hh) * TT + r0 + rl];
        Ls[rl][hh] = 1.0f / L;
    }
    __syncthreads();
    const int rl = t >> 5, lane = t & 31;
    const int row = r0 + rl;
#pragma unroll
    for (int j = 0; j < 3; ++j) {
        const int d0 = lane * 8 + j * 256;
        float acc[8];
#pragma unroll
        for (int e = 0; e < 8; ++e) acc[e] = 0.f;
#pragma unroll
        for (int p = 0; p < SP; ++p) {
            const bf16x8 vv = *(const bf16x8*)&Opb[((size_t)p * TT + row) * DM + d0];
#pragma unroll
            for (int e = 0; e < 8; ++e) acc[e] += (float)vv[e];
        }
        const float s = Ls[rl][d0 / DKH];
        bf16x8 o;
#pragma unroll
        for (int e = 0; e < 8; ++e) o[e] = (__bf16)(acc[e] * s);
        *(bf16x8*)&ob[(size_t)row * DM + d0] = o;
    }
}

// x = LN(r) * g + be   (residual already folded into r by the GEMM epilogue)
__global__ __launch_bounds__(256) void ln_only(bf16* __restrict__ x,
                                               const bf16* __restrict__ r,
                                               const float* __restrict__ g,
                                               const float* __restrict__ be) {
    __shared__ float red[4];
    const int row = blockIdx.x;
    bf16* xr = x + (size_t)row * DM;
    const bf16* rr = r + (size_t)row * DM;
    const int t = threadIdx.x;

    float v0 = b2f(rr[t]);
    float v1 = b2f(rr[t + 256]);
    float v2 = b2f(rr[t + 512]);
    float s = v0 + v1 + v2;
#pragma unroll
    for (int off = 32; off >= 1; off >>= 1) s += __shfl_xor(s, off);
    if ((t & 63) == 0) red[t >> 6] = s;
    __syncthreads();
    s = red[0] + red[1] + red[2] + red[3];
    const float mean = s * (1.f / 768.f);
    __syncthreads();

    const float d0 = v0 - mean, d1 = v1 - mean, d2 = v2 - mean;
    float ss = d0 * d0 + d1 * d1 + d2 * d2;
#pragma unroll
    for (int off = 32; off >= 1; off >>= 1) ss += __shfl_xor(ss, off);
    if ((t & 63) == 0) red[t >> 6] = ss;
    __syncthreads();
    ss = red[0] + red[1] + red[2] + red[3];
    const float inv = rsqrtf(ss * (1.f / 768.f) + LN_EPS);

    xr[t]       = f2b(d0 * inv * g[t]       + be[t]);
    xr[t + 256] = f2b(d1 * inv * g[t + 256] + be[t + 256]);
    xr[t + 512] = f2b(d2 * inv * g[t + 512] + be[t + 512]);
}

// fallback: x = LN(x + r) * g + be
__global__ __launch_bounds__(256) void add_ln(bf16* __restrict__ x,
                                              const bf16* __restrict__ r,
                                              const float* __restrict__ g,
                                              const float* __restrict__ be) {
    __shared__ float red[4];
    const int row = blockIdx.x;
    bf16* xr = x + (size_t)row * DM;
    const bf16* rr = r + (size_t)row * DM;
    const int t = threadIdx.x;

    float v0 = b2f(xr[t]) + b2f(rr[t]);
    float v1 = b2f(xr[t + 256]) + b2f(rr[t + 256]);
    float v2 = b2f(xr[t + 512]) + b2f(rr[t + 512]);
    float s = v0 + v1 + v2;
#pragma unroll
    for (int off = 32; off >= 1; off >>= 1) s += __shfl_xor(s, off);
    if ((t & 63) == 0) red[t >> 6] = s;
    __syncthreads();
    s = red[0] + red[1] + red[2] + red[3];
    const float mean = s * (1.f / 768.f);
    __syncthreads();

    const float d0 = v0 - mean, d1 = v1 - mean, d2 = v2 - mean;
    float ss = d0 * d0 + d1 * d1 + d2 * d2;
#pragma unroll
    for (int off = 32; off >= 1; off >>= 1) ss += __shfl_xor(ss, off);
    if ((t & 63) == 0) red[t >> 6] = ss;
    __syncthreads();
    ss = red[0] + red[1] + red[2] + red[3];
    const float inv = rsqrtf(ss * (1.f / 768.f) + LN_EPS);

    xr[t]       = f2b(d0 * inv * g[t]       + be[t]);
    xr[t + 256] = f2b(d1 * inv * g[t + 256] + be[t + 256]);
    xr[t + 512] = f2b(d2 * inv * g[t + 512] + be[t + 512]);
}

__global__ __launch_bounds__(256) void predict(const bf16* __restrict__ x,
                                               const float* __restrict__ ng,
                                               const float* __restrict__ nb,
                                               const float* __restrict__ Wp,
                                               const float* __restrict__ bp,
                                               float* __restrict__ out) {
    __shared__ float xs[BAG][DM];
    __shared__ float red[4][BAG];
    const int t = threadIdx.x;
    const int rel = blockIdx.x;
    const int wid = t >> 6, lane = t & 63;

    for (int rep = 0; rep < 2; ++rep) {
        const int b = wid + rep * 4;
        const bf16* row = x + (size_t)(294 * b + 1) * DM;
        float vals[12];
        float s = 0.f;
#pragma unroll
        for (int i = 0; i < 12; ++i) { vals[i] = b2f(row[lane + i * 64]); s += vals[i]; }
#pragma unroll
        for (int off = 32; off >= 1; off >>= 1) s += __shfl_xor(s, off);
        const float mean = s * (1.f / 768.f);
        float ss = 0.f;
#pragma unroll
        for (int i = 0; i < 12; ++i) { const float d = vals[i] - mean; ss += d * d; }
#pragma unroll
        for (int off = 32; off >= 1; off >>= 1) ss += __shfl_xor(ss, off);
        const float inv = rsqrtf(ss * (1.f / 768.f) + LN_EPS);
#pragma unroll
        for (int i = 0; i < 12; ++i) {
            const int d = lane + i * 64;
            xs[b][d] = (vals[i] - mean) * inv * ng[d] + nb[d];
        }
    }
    __syncthreads();

    float pb[BAG];
#pragma unroll
    for (int b = 0; b < BAG; ++b) pb[b] = 0.f;
    for (int k = t; k < DM; k += 256) {
        const float wv = Wp[(size_t)k * NREL + rel];
#pragma unroll
        for (int b = 0; b < BAG; ++b) pb[b] += xs[b][k] * wv;
    }
#pragma unroll
    for (int b = 0; b < BAG; ++b)
#pragma unroll
        for (int off = 32; off >= 1; off >>= 1) pb[b] += __shfl_xor(pb[b], off);
    if (lane == 0)
#pragma unroll
        for (int b = 0; b < BAG; ++b) red[wid][b] = pb[b];
    __syncthreads();
    if (t == 0) {
        float mx = -3.0e38f;
        for (int b = 0; b < BAG; ++b) {
            const float v = red[0][b] + red[1][b] + red[2][b] + red[3][b] + bp[rel];
            out[NREL + b * NREL + rel] = v;
            mx = fmaxf(mx, v);
        }
        out[rel] = mx;
    }
}

// ---------------------------------------------------------------------------
// host. ws layout (bytes), high-water 48,635,904:
//   htb 0 | u2 73728 (48x1536 fused u|v) | x 221184 | Bq 3760128
//   Bk 7299072 | Bv 10838016 | Vt 15556608 | slab 19095552 | Opb 26959872
//   (SP=6 bf16, 21.2 MB) | Lp 48193536
// ---------------------------------------------------------------------------
extern "C" void kernel_launch(void* const* d_in, const int* in_sizes, int n_in,
                              void* d_out, int out_size, void* d_ws, size_t ws_size,
                              hipStream_t stream) {
    const float* emb  = (const float*)d_in[0];
    const int* spans  = (const int*)d_in[1];
    const float* Wu = (const float*)d_in[2];  const float* bu = (const float*)d_in[3];
    const float* Wv = (const float*)d_in[4];  const float* bv = (const float*)d_in[5];
    const float* Wl = (const float*)d_in[6];  const float* bl = (const float*)d_in[7];
    const float* Wq = (const float*)d_in[8];  const float* bq = (const float*)d_in[9];
    const float* Wk = (const float*)d_in[10]; const float* bk = (const float*)d_in[11];
    const float* Wvm = (const float*)d_in[12]; const float* bvm = (const float*)d_in[13];
    const float* Wo = (const float*)d_in[14]; const float* bo = (const float*)d_in[15];
    const float* F1 = (const float*)d_in[16]; const float* f1 = (const float*)d_in[17];
    const float* F2 = (const float*)d_in[18]; const float* f2 = (const float*)d_in[19];
    const float* g1 = (const float*)d_in[20]; const float* be1 = (const float*)d_in[21];
    const float* g2 = (const float*)d_in[22]; const float* be2 = (const float*)d_in[23];
    const float* ng = (const float*)d_in[24]; const float* nb = (const float*)d_in[25];
    const float* Wp = (const float*)d_in[26]; const float* bp = (const float*)d_in[27];

    char* wsb = (char*)d_ws;
    bf16* htb = (bf16*)(wsb + 0);
    bf16* u2  = (bf16*)(wsb + 73728);     // full path: 48x1536 fused u|v
    bf16* ub  = (bf16*)(wsb + 73728);     // fallback: 48x768
    bf16* vbn = (bf16*)(wsb + 147456);    // fallback: 48x768
    bf16* x   = (bf16*)(wsb + 221184);
    bf16* Bq  = (bf16*)(wsb + 3760128);
    bf16* Bk  = (bf16*)(wsb + 7299072);
    bf16* Bv  = (bf16*)(wsb + 10838016);
    bf16* Vt  = (bf16*)(wsb + 15556608);
    bf16* slab = (bf16*)(wsb + 19095552);
    bf16* Opb = (bf16*)(wsb + 26959872);
    float* Lp = (float*)(wsb + 48193536);

    const size_t FULL_END = 48635904;
    const bool use_full = ws_size >= FULL_END;

    span_pool<<<dim3(NNODE, 6), 128, 0, stream>>>(emb, spans, htb);

    if (use_full) {
        prep_wt3<<<dim3(12, 12, 3), 256, 0, stream>>>(Wu, Wv, Wl, slab);
        // fused u|v GEMM: Bt = [Wu^T ; Wv^T] contiguous in slab, N=1536
        gemm_bt256<0, 1, 0><<<dim3(24, 1), 256, 0, stream>>>(htb, slab, bu, bv, nullptr, u2,
                                                             NNODE, 2 * DM, DM);
        // rel GEMM with fused relu(u_i+v_j) A-staging
        gemm_rel<<<dim3(12, TT / 64), 256, 0, stream>>>(u2, slab + 1179648, bl, x);

        for (int l = 0; l < NLAYER; ++l) {
            const size_t wo = (size_t)l * DM * DM;
            const size_t f1o = (size_t)l * DM * DFF;
            prep6<<<dim3(16, 16, 6), 256, 0, stream>>>(Wq + wo, Wk + wo, Wvm + wo,
                                                       Wo + wo, F1 + f1o, F2 + f1o, slab);
            gemm_qkv256<<<dim3(36, TT / 64), 256, 0, stream>>>(x, slab, bq + l * DM, bk + l * DM,
                                                               bvm + l * DM, Bq, Bk, Vt);
            attn_mfma<1><<<dim3(36 * NH * SP), 256, 0, stream>>>(Bq, Bk, Vt, Bq, Opb, Lp, KSPAN);
            attn_merge<<<TT / 8, 256, 0, stream>>>(Opb, Lp, Bq);
            // Wo GEMM with residual fused: Bk = o@Wo + bo + x
            gemm_bt256<0, 0, 1><<<dim3(12, TT / 64), 256, 0, stream>>>(Bq, slab + 1769472, bo + l * DM,
                                                                       bo + l * DM, x, Bk, TT, DM, DM);
            ln_only<<<TT, 256, 0, stream>>>(x, Bk, g1 + l * DM, be1 + l * DM);
            gemm_bt256<1, 0, 0><<<dim3(16, TT / 64), 256, 0, stream>>>(x, slab + 2359296, f1 + l * DFF,
                                                                       f1 + l * DFF, nullptr, Bv, TT, DFF, DM);
            // FFN2 GEMM with residual fused: Bk = h@F2 + f2 + x
            gemm_bt256<0, 0, 1><<<dim3(12, TT / 64), 256, 0, stream>>>(Bv, slab + 3145728, f2 + l * DM,
                                                                       f2 + l * DM, x, Bk, TT, DM, DFF);
            ln_only<<<TT, 256, 0, stream>>>(x, Bk, g2 + l * DM, be2 + l * DM);
        }
    } else {
        gemm_mfma<0><<<dim3(12, 2), 128, 0, stream>>>(htb, Wu, bu, ub, NNODE, DM, DM);
        gemm_mfma<0><<<dim3(12, 2), 128, 0, stream>>>(htb, Wv, bv, vbn, NNODE, DM, DM);
        build_relA<<<TT, 256, 0, stream>>>(ub, vbn, DM, Bq);
        gemm_mfma<1><<<dim3(12, TT / 32), 128, 0, stream>>>(Bq, Wl, bl, x, TT, DM, DM);

        for (int l = 0; l < NLAYER; ++l) {
            const size_t wo = (size_t)l * DM * DM;
            const size_t f1o = (size_t)l * DM * DFF;
            gemm_mfma<0><<<dim3(12, TT / 32), 128, 0, stream>>>(x, Wq + wo, bq + l * DM, Bq, TT, DM, DM);
            gemm_mfma<0><<<dim3(12, TT / 32), 128, 0, stream>>>(x, Wk + wo, bk + l * DM, Bk, TT, DM, DM);
            gemm_mfma<0><<<dim3(12, TT / 32), 128, 0, stream>>>(x, Wvm + wo, bvm + l * DM, Bv, TT, DM, DM);
            transpose_v<<<dim3(DM / 64, TT / 64), 256, 0, stream>>>(Bv, Vt);
            attn_mfma<0><<<dim3(36 * NH), 256, 0, stream>>>(Bq, Bk, Vt, Bq, Opb, Lp, TT);
            gemm_mfma<0><<<dim3(12, TT / 32), 128, 0, stream>>>(Bq, Wo + wo, bo + l * DM, Bk, TT, DM, DM);
            add_ln<<<TT, 256, 0, stream>>>(x, Bk, g1 + l * DM, be1 + l * DM);
            gemm_mfma<1><<<dim3(16, TT / 32), 128, 0, stream>>>(x, F1 + f1o, f1 + l * DFF, Bv, TT, DFF, DM);
            gemm_mfma<0><<<dim3(12, TT / 32), 128, 0, stream>>>(Bv, F2 + f1o, f2 + l * DM, Bk, TT, DM, DFF);
            add_ln<<<TT, 256, 0, stream>>>(x, Bk, g2 + l * DM, be2 + l * DM);
        }
    }

    predict<<<NREL, 256, 0, stream>>>(x, ng, nb, Wp, bp, (float*)d_out);
}

// Round 6
// 630.904 us; speedup vs baseline: 1.0522x; 1.0522x over previous
//
#include <hip/hip_runtime.h>
#include <hip/hip_bf16.h>

typedef __hip_bfloat16 bf16;
typedef __bf16 bf16x8 __attribute__((ext_vector_type(8)));
typedef float f32x4 __attribute__((ext_vector_type(4)));

#define BAG 8
#define SEQ 512
#define DM 768
#define NPD 6
#define NNODE 48
#define TT 2304
#define NH 8
#define DKH 96
#define DFF 1024
#define NLAYER 4
#define NREL 97
#define SP 6
#define KSPAN (TT / SP)
#define LN_EPS 1e-5f

__device__ __forceinline__ float b2f(const bf16 x) { return __bfloat162float(x); }
__device__ __forceinline__ bf16 f2b(float f) { return __float2bfloat16(f); }
__device__ __forceinline__ unsigned short f2bu(float f) {
    bf16 h = __float2bfloat16(f);
    return *reinterpret_cast<unsigned short*>(&h);
}

__global__ __launch_bounds__(128) void span_pool(const float* __restrict__ emb,
                                                 const int* __restrict__ spans,
                                                 bf16* __restrict__ htb) {
    const int n = blockIdx.x;
    const int b = n / NPD;
    int s0 = spans[n * 2 + 0];
    int s1 = spans[n * 2 + 1];
    s0 = min(max(s0, 0), SEQ - 1);
    s1 = min(max(s1, s0), SEQ - 1);
    const float* base = emb + (size_t)b * SEQ * DM;
    const int d = blockIdx.y * 128 + threadIdx.x;
    float m = -3.0e38f;
    for (int s = s0; s <= s1; ++s) m = fmaxf(m, base[(size_t)s * DM + d]);
    htb[(size_t)n * DM + d] = f2b(m);
}

// ---------------------------------------------------------------------------
// weight prep (3 DMxDM): W[K][N] f32 -> Wt[N][K] bf16, out at z*DM*DM
// ---------------------------------------------------------------------------
__global__ __launch_bounds__(256) void prep_wt3(const float* __restrict__ W0,
                                                const float* __restrict__ W1,
                                                const float* __restrict__ W2,
                                                bf16* __restrict__ Wt) {
    __shared__ __align__(16) __bf16 tile[64][72];
    const int z = blockIdx.z;
    const float* W = (z == 0) ? W0 : (z == 1) ? W1 : W2;
    bf16* out = Wt + (size_t)z * DM * DM;
    const int t = threadIdx.x;
    const int k0 = blockIdx.x * 64, n0 = blockIdx.y * 64;
    const int r = t >> 2, cg = (t & 3) * 16;
#pragma unroll
    for (int i = 0; i < 4; ++i) {
        const float4 v = *(const float4*)&W[(size_t)(k0 + r) * DM + n0 + cg + 4 * i];
        tile[r][cg + 4 * i + 0] = (__bf16)v.x;
        tile[r][cg + 4 * i + 1] = (__bf16)v.y;
        tile[r][cg + 4 * i + 2] = (__bf16)v.z;
        tile[r][cg + 4 * i + 3] = (__bf16)v.w;
    }
    __syncthreads();
#pragma unroll
    for (int i = 0; i < 2; ++i) {
        bf16x8 o;
#pragma unroll
        for (int j = 0; j < 8; ++j) o[j] = tile[cg + 8 * i + j][r];
        *(bf16x8*)&out[(size_t)(n0 + r) * DM + k0 + cg + 8 * i] = o;
    }
}

// ---------------------------------------------------------------------------
// prep6: one launch converts Wq,Wk,Wv,Wo,F1,F2 -> transposed bf16 slab.
// ---------------------------------------------------------------------------
__global__ __launch_bounds__(256) void prep6(const float* __restrict__ Wq,
                                             const float* __restrict__ Wk,
                                             const float* __restrict__ Wv,
                                             const float* __restrict__ Wo,
                                             const float* __restrict__ F1,
                                             const float* __restrict__ F2,
                                             bf16* __restrict__ slab) {
    __shared__ __align__(16) __bf16 tile[64][72];
    const int z = blockIdx.z;
    int K = DM, N = DM;
    const float* W;
    size_t off;
    switch (z) {
        case 0: W = Wq; off = 0;       break;
        case 1: W = Wk; off = 589824;  break;
        case 2: W = Wv; off = 1179648; break;
        case 3: W = Wo; off = 1769472; break;
        case 4: W = F1; off = 2359296; N = DFF; break;
        default: W = F2; off = 3145728; K = DFF; break;
    }
    const int k0 = blockIdx.x * 64, n0 = blockIdx.y * 64;
    if (k0 >= K || n0 >= N) return;
    bf16* out = slab + off;
    const int t = threadIdx.x;
    const int r = t >> 2, cg = (t & 3) * 16;
#pragma unroll
    for (int i = 0; i < 4; ++i) {
        const float4 v = *(const float4*)&W[(size_t)(k0 + r) * N + n0 + cg + 4 * i];
        tile[r][cg + 4 * i + 0] = (__bf16)v.x;
        tile[r][cg + 4 * i + 1] = (__bf16)v.y;
        tile[r][cg + 4 * i + 2] = (__bf16)v.z;
        tile[r][cg + 4 * i + 3] = (__bf16)v.w;
    }
    __syncthreads();
#pragma unroll
    for (int i = 0; i < 2; ++i) {
        bf16x8 o;
#pragma unroll
        for (int j = 0; j < 8; ++j) o[j] = tile[cg + 8 * i + j][r];
        *(bf16x8*)&out[(size_t)(n0 + r) * K + k0 + cg + 8 * i] = o;
    }
}

// ---------------------------------------------------------------------------
// MFMA GEMM v3: 64x64 tile, 256 threads = 4 waves in 2x2 grid, BK=64,
// double-buffered LDS (36864 B -> 4 blocks/CU), one barrier per K-iter.
// DUAL=1: bias is split [bias | bias2] at col DM (for fused u/v GEMM).
// (No XCD swizzle: these GEMMs are L2/L3-resident; r5 showed swizzle hurts.)
// ---------------------------------------------------------------------------
template <int RELU, int DUAL>
__global__ __launch_bounds__(256) void gemm_bt256(const bf16* __restrict__ A,
                                                  const bf16* __restrict__ Bt,
                                                  const float* __restrict__ bias,
                                                  const float* __restrict__ bias2,
                                                  bf16* __restrict__ C,
                                                  int M, int N, int K) {
    __shared__ __align__(16) __bf16 As[2][64][72];
    __shared__ __align__(16) __bf16 Bs[2][64][72];
    const int t = threadIdx.x;
    const int w = t >> 6, lane = t & 63;
    const int quad = lane >> 4, l15 = lane & 15;
    const int wr = w >> 1, wc = w & 1;            // 2x2 wave grid
    const int row0 = blockIdx.y * 64, col0 = blockIdx.x * 64;
    const int s_row = t >> 2, s_off = (t & 3) * 16;
    const bool a_ok = (row0 + s_row) < M;

    const f32x4 fz = {0.f, 0.f, 0.f, 0.f};
    f32x4 acc[2][2];
#pragma unroll
    for (int m = 0; m < 2; ++m)
#pragma unroll
        for (int n = 0; n < 2; ++n) acc[m][n] = fz;

    bf16x8 av[2], bv[2];
#pragma unroll
    for (int j = 0; j < 2; ++j)
#pragma unroll
        for (int e = 0; e < 8; ++e) av[j][e] = (__bf16)0.0f;
    if (a_ok)
#pragma unroll
        for (int j = 0; j < 2; ++j)
            av[j] = *(const bf16x8*)&A[(size_t)(row0 + s_row) * K + s_off + 8 * j];
#pragma unroll
    for (int j = 0; j < 2; ++j)
        bv[j] = *(const bf16x8*)&Bt[(size_t)(col0 + s_row) * K + s_off + 8 * j];

    int cur = 0;
    for (int k0 = 0; k0 < K; k0 += 64) {
#pragma unroll
        for (int j = 0; j < 2; ++j) {
            *(bf16x8*)&As[cur][s_row][s_off + 8 * j] = av[j];
            *(bf16x8*)&Bs[cur][s_row][s_off + 8 * j] = bv[j];
        }
        __syncthreads();

        if (k0 + 64 < K) {
            if (a_ok)
#pragma unroll
                for (int j = 0; j < 2; ++j)
                    av[j] = *(const bf16x8*)&A[(size_t)(row0 + s_row) * K + k0 + 64 + s_off + 8 * j];
#pragma unroll
            for (int j = 0; j < 2; ++j)
                bv[j] = *(const bf16x8*)&Bt[(size_t)(col0 + s_row) * K + k0 + 64 + s_off + 8 * j];
        }

#pragma unroll
        for (int kk = 0; kk < 2; ++kk) {
            const bf16x8 af0 = *(const bf16x8*)&As[cur][wr * 32 + l15][quad * 8 + 32 * kk];
            const bf16x8 af1 = *(const bf16x8*)&As[cur][wr * 32 + 16 + l15][quad * 8 + 32 * kk];
            const bf16x8 bf0 = *(const bf16x8*)&Bs[cur][wc * 32 + l15][quad * 8 + 32 * kk];
            const bf16x8 bf1 = *(const bf16x8*)&Bs[cur][wc * 32 + 16 + l15][quad * 8 + 32 * kk];
            acc[0][0] = __builtin_amdgcn_mfma_f32_16x16x32_bf16(af0, bf0, acc[0][0], 0, 0, 0);
            acc[0][1] = __builtin_amdgcn_mfma_f32_16x16x32_bf16(af0, bf1, acc[0][1], 0, 0, 0);
            acc[1][0] = __builtin_amdgcn_mfma_f32_16x16x32_bf16(af1, bf0, acc[1][0], 0, 0, 0);
            acc[1][1] = __builtin_amdgcn_mfma_f32_16x16x32_bf16(af1, bf1, acc[1][1], 0, 0, 0);
        }
        cur ^= 1;
    }

#pragma unroll
    for (int n = 0; n < 2; ++n) {
        const int col = col0 + wc * 32 + 16 * n + l15;
        const float bvl = (DUAL && col >= DM) ? bias2[col - DM] : bias[col];
#pragma unroll
        for (int m = 0; m < 2; ++m)
#pragma unroll
            for (int r = 0; r < 4; ++r) {
                const int row = row0 + wr * 32 + 16 * m + quad * 4 + r;
                if (row < M) {
                    float v = acc[m][n][r] + bvl;
                    if (RELU) v = fmaxf(v, 0.f);
                    C[(size_t)row * N + col] = f2b(v);
                }
            }
    }
}

// ---------------------------------------------------------------------------
// gemm_rel: rel GEMM with build_relA FUSED into A-staging:
// A[cell][k] = relu(u2[i][k] + u2[j][768+k]), cell = i*48+j.
// ---------------------------------------------------------------------------
__global__ __launch_bounds__(256) void gemm_rel(const bf16* __restrict__ u2,
                                                const bf16* __restrict__ Bt,
                                                const float* __restrict__ bias,
                                                bf16* __restrict__ C) {
    __shared__ __align__(16) __bf16 As[2][64][72];
    __shared__ __align__(16) __bf16 Bs[2][64][72];
    const int t = threadIdx.x;
    const int w = t >> 6, lane = t & 63;
    const int quad = lane >> 4, l15 = lane & 15;
    const int wr = w >> 1, wc = w & 1;
    const int row0 = blockIdx.y * 64, col0 = blockIdx.x * 64;
    const int s_row = t >> 2, s_off = (t & 3) * 16;
    const int cell = row0 + s_row;
    const bf16* up = u2 + (size_t)(cell / NNODE) * (2 * DM);
    const bf16* vp = u2 + (size_t)(cell % NNODE) * (2 * DM) + DM;

    const f32x4 fz = {0.f, 0.f, 0.f, 0.f};
    f32x4 acc[2][2];
#pragma unroll
    for (int m = 0; m < 2; ++m)
#pragma unroll
        for (int n = 0; n < 2; ++n) acc[m][n] = fz;

    bf16x8 uu[2], vv[2], bv[2];
#pragma unroll
    for (int j = 0; j < 2; ++j) {
        uu[j] = *(const bf16x8*)&up[s_off + 8 * j];
        vv[j] = *(const bf16x8*)&vp[s_off + 8 * j];
        bv[j] = *(const bf16x8*)&Bt[(size_t)(col0 + s_row) * DM + s_off + 8 * j];
    }

    int cur = 0;
    for (int k0 = 0; k0 < DM; k0 += 64) {
#pragma unroll
        for (int j = 0; j < 2; ++j) {
            bf16x8 o;
#pragma unroll
            for (int e = 0; e < 8; ++e)
                o[e] = (__bf16)fmaxf((float)uu[j][e] + (float)vv[j][e], 0.f);
            *(bf16x8*)&As[cur][s_row][s_off + 8 * j] = o;
            *(bf16x8*)&Bs[cur][s_row][s_off + 8 * j] = bv[j];
        }
        __syncthreads();

        if (k0 + 64 < DM) {
#pragma unroll
            for (int j = 0; j < 2; ++j) {
                uu[j] = *(const bf16x8*)&up[k0 + 64 + s_off + 8 * j];
                vv[j] = *(const bf16x8*)&vp[k0 + 64 + s_off + 8 * j];
                bv[j] = *(const bf16x8*)&Bt[(size_t)(col0 + s_row) * DM + k0 + 64 + s_off + 8 * j];
            }
        }

#pragma unroll
        for (int kk = 0; kk < 2; ++kk) {
            const bf16x8 af0 = *(const bf16x8*)&As[cur][wr * 32 + l15][quad * 8 + 32 * kk];
            const bf16x8 af1 = *(const bf16x8*)&As[cur][wr * 32 + 16 + l15][quad * 8 + 32 * kk];
            const bf16x8 bf0 = *(const bf16x8*)&Bs[cur][wc * 32 + l15][quad * 8 + 32 * kk];
            const bf16x8 bf1 = *(const bf16x8*)&Bs[cur][wc * 32 + 16 + l15][quad * 8 + 32 * kk];
            acc[0][0] = __builtin_amdgcn_mfma_f32_16x16x32_bf16(af0, bf0, acc[0][0], 0, 0, 0);
            acc[0][1] = __builtin_amdgcn_mfma_f32_16x16x32_bf16(af0, bf1, acc[0][1], 0, 0, 0);
            acc[1][0] = __builtin_amdgcn_mfma_f32_16x16x32_bf16(af1, bf0, acc[1][0], 0, 0, 0);
            acc[1][1] = __builtin_amdgcn_mfma_f32_16x16x32_bf16(af1, bf1, acc[1][1], 0, 0, 0);
        }
        cur ^= 1;
    }

#pragma unroll
    for (int n = 0; n < 2; ++n) {
        const int col = col0 + wc * 32 + 16 * n + l15;
        const float bvl = bias[col];
#pragma unroll
        for (int m = 0; m < 2; ++m)
#pragma unroll
            for (int r = 0; r < 4; ++r) {
                const int row = row0 + wr * 32 + 16 * m + quad * 4 + r;
                C[(size_t)row * DM + col] = f2b(fmaxf(acc[m][n][r] + bvl, 0.f));
            }
    }
}

// ---------------------------------------------------------------------------
// fused QKV GEMM: 64x64 tile, 256 threads, double-buffered. V tiles
// (col0 >= 2*DM) written TRANSPOSED to Vt[768][TT] via LDS bounce.
// ---------------------------------------------------------------------------
__global__ __launch_bounds__(256) void gemm_qkv256(const bf16* __restrict__ A,
                                                   const bf16* __restrict__ Bt,
                                                   const float* __restrict__ b0,
                                                   const float* __restrict__ b1,
                                                   const float* __restrict__ b2,
                                                   bf16* __restrict__ C0,
                                                   bf16* __restrict__ C1,
                                                   bf16* __restrict__ Vt) {
    __shared__ __align__(16) __bf16 As[2][64][72];
    __shared__ __align__(16) __bf16 Bs[2][64][72];
    const int t = threadIdx.x;
    const int w = t >> 6, lane = t & 63;
    const int quad = lane >> 4, l15 = lane & 15;
    const int wr = w >> 1, wc = w & 1;
    const int row0 = blockIdx.y * 64, col0 = blockIdx.x * 64;
    const int s_row = t >> 2, s_off = (t & 3) * 16;

    const f32x4 fz = {0.f, 0.f, 0.f, 0.f};
    f32x4 acc[2][2];
#pragma unroll
    for (int m = 0; m < 2; ++m)
#pragma unroll
        for (int n = 0; n < 2; ++n) acc[m][n] = fz;

    bf16x8 av[2], bv[2];
#pragma unroll
    for (int j = 0; j < 2; ++j) {
        av[j] = *(const bf16x8*)&A[(size_t)(row0 + s_row) * DM + s_off + 8 * j];
        bv[j] = *(const bf16x8*)&Bt[(size_t)(col0 + s_row) * DM + s_off + 8 * j];
    }

    int cur = 0;
    for (int k0 = 0; k0 < DM; k0 += 64) {
#pragma unroll
        for (int j = 0; j < 2; ++j) {
            *(bf16x8*)&As[cur][s_row][s_off + 8 * j] = av[j];
            *(bf16x8*)&Bs[cur][s_row][s_off + 8 * j] = bv[j];
        }
        __syncthreads();

        if (k0 + 64 < DM) {
#pragma unroll
            for (int j = 0; j < 2; ++j) {
                av[j] = *(const bf16x8*)&A[(size_t)(row0 + s_row) * DM + k0 + 64 + s_off + 8 * j];
                bv[j] = *(const bf16x8*)&Bt[(size_t)(col0 + s_row) * DM + k0 + 64 + s_off + 8 * j];
            }
        }

#pragma unroll
        for (int kk = 0; kk < 2; ++kk) {
            const bf16x8 af0 = *(const bf16x8*)&As[cur][wr * 32 + l15][quad * 8 + 32 * kk];
            const bf16x8 af1 = *(const bf16x8*)&As[cur][wr * 32 + 16 + l15][quad * 8 + 32 * kk];
            const bf16x8 bf0 = *(const bf16x8*)&Bs[cur][wc * 32 + l15][quad * 8 + 32 * kk];
            const bf16x8 bf1 = *(const bf16x8*)&Bs[cur][wc * 32 + 16 + l15][quad * 8 + 32 * kk];
            acc[0][0] = __builtin_amdgcn_mfma_f32_16x16x32_bf16(af0, bf0, acc[0][0], 0, 0, 0);
            acc[0][1] = __builtin_amdgcn_mfma_f32_16x16x32_bf16(af0, bf1, acc[0][1], 0, 0, 0);
            acc[1][0] = __builtin_amdgcn_mfma_f32_16x16x32_bf16(af1, bf0, acc[1][0], 0, 0, 0);
            acc[1][1] = __builtin_amdgcn_mfma_f32_16x16x32_bf16(af1, bf1, acc[1][1], 0, 0, 0);
        }
        cur ^= 1;
    }

    const int buf = col0 / DM;
    const int lc0 = col0 - buf * DM;
    if (buf < 2) {
        bf16* Cb = (buf == 0) ? C0 : C1;
        const float* bb = (buf == 0) ? b0 : b1;
#pragma unroll
        for (int n = 0; n < 2; ++n) {
            const int col = lc0 + wc * 32 + 16 * n + l15;
            const float bvl = bb[col];
#pragma unroll
            for (int m = 0; m < 2; ++m)
#pragma unroll
                for (int r = 0; r < 4; ++r) {
                    const int row = row0 + wr * 32 + 16 * m + quad * 4 + r;
                    Cb[(size_t)row * DM + col] = f2b(acc[m][n][r] + bvl);
                }
        }
    } else {
        __bf16 (*Tb)[72] = As[0];   // [col_local][row_local]
        __syncthreads();
#pragma unroll
        for (int n = 0; n < 2; ++n) {
            const int cl = wc * 32 + 16 * n + l15;
            const float bvl = b2[lc0 + cl];
#pragma unroll
            for (int m = 0; m < 2; ++m)
#pragma unroll
                for (int r = 0; r < 4; ++r)
                    Tb[cl][wr * 32 + 16 * m + quad * 4 + r] = (__bf16)(acc[m][n][r] + bvl);
        }
        __syncthreads();
        const int c = t >> 2, seg = (t & 3) * 16;
        const bf16x8 o0 = *(const bf16x8*)&Tb[c][seg];
        const bf16x8 o1 = *(const bf16x8*)&Tb[c][seg + 8];
        *(bf16x8*)&Vt[(size_t)(lc0 + c) * TT + row0 + seg] = o0;
        *(bf16x8*)&Vt[(size_t)(lc0 + c) * TT + row0 + seg + 8] = o1;
    }
}

// fallback GEMM (f32 weights, staging conversion)
template <int RELU>
__global__ __launch_bounds__(128) void gemm_mfma(const bf16* __restrict__ A,
                                                 const float* __restrict__ W,
                                                 const float* __restrict__ bias,
                                                 bf16* __restrict__ C,
                                                 int M, int N, int K) {
    __shared__ __align__(16) __bf16 As[32][40];
    __shared__ __align__(16) __bf16 Bs[64][40];
    const int t = threadIdx.x;
    const int w = t >> 6, lane = t & 63;
    const int quad = lane >> 4, l15 = lane & 15;
    const int row0 = blockIdx.y * 32, col0 = blockIdx.x * 64;
    const int s_row = t >> 2, s_kg = (t & 3) * 8;
    const int s_colg = (t & 15) * 4, s_kp = t >> 4;
    const bool a_ok = (row0 + s_row) < M;
    const f32x4 fz = {0.f, 0.f, 0.f, 0.f};
    f32x4 acc[4];
#pragma unroll
    for (int i = 0; i < 4; ++i) acc[i] = fz;

    for (int k0 = 0; k0 < K; k0 += 32) {
        bf16x8 av;
        for (int j = 0; j < 8; ++j) av[j] = (__bf16)0.0f;
        if (a_ok) av = *(const bf16x8*)&A[(size_t)(row0 + s_row) * K + k0 + s_kg];
        *(bf16x8*)&As[s_row][s_kg] = av;
#pragma unroll
        for (int rep = 0; rep < 2; ++rep) {
            const int kp = s_kp + 8 * rep;
            const size_t gb = (size_t)(k0 + 2 * kp) * N + col0 + s_colg;
            const float4 w0 = *(const float4*)&W[gb];
            const float4 w1 = *(const float4*)&W[gb + N];
#pragma unroll
            for (int i = 0; i < 4; ++i) {
                ushort2 pk;
                pk.x = f2bu((&w0.x)[i]);
                pk.y = f2bu((&w1.x)[i]);
                *(ushort2*)&Bs[s_colg + i][2 * kp] = pk;
            }
        }
        __syncthreads();
        const bf16x8 af = *(const bf16x8*)&As[16 * w + l15][quad * 8];
#pragma unroll
        for (int nt = 0; nt < 4; ++nt) {
            const bf16x8 bfv = *(const bf16x8*)&Bs[16 * nt + l15][quad * 8];
            acc[nt] = __builtin_amdgcn_mfma_f32_16x16x32_bf16(af, bfv, acc[nt], 0, 0, 0);
        }
        __syncthreads();
    }
#pragma unroll
    for (int nt = 0; nt < 4; ++nt) {
        const int col = col0 + 16 * nt + l15;
        const float bvl = bias[col];
#pragma unroll
        for (int r = 0; r < 4; ++r) {
            const int row = row0 + 16 * w + quad * 4 + r;
            if (row < M) {
                float v = acc[nt][r] + bvl;
                if (RELU) v = fmaxf(v, 0.f);
                C[(size_t)row * N + col] = f2b(v);
            }
        }
    }
}

// build_relA (fallback path only)
__global__ __launch_bounds__(256) void build_relA(const bf16* __restrict__ u,
                                                  const bf16* __restrict__ v,
                                                  int stride,
                                                  bf16* __restrict__ A) {
    const int cell = blockIdx.x;
    const int i = cell / NNODE, j = cell % NNODE;
    for (int k = threadIdx.x; k < DM; k += 256) {
        A[(size_t)cell * DM + k] =
            f2b(fmaxf(b2f(u[(size_t)i * stride + k]) + b2f(v[(size_t)j * stride + k]), 0.f));
    }
}

__global__ __launch_bounds__(256) void transpose_v(const bf16* __restrict__ v,
                                                   bf16* __restrict__ vt) {
    __shared__ __align__(16) __bf16 tile[64][72];
    const int t = threadIdx.x;
    const int bx = blockIdx.x, by = blockIdx.y;
    const int r = t >> 2, cg = (t & 3) * 16;
#pragma unroll
    for (int i = 0; i < 2; ++i)
        *(bf16x8*)&tile[r][cg + 8 * i] =
            *(const bf16x8*)&v[(size_t)(by * 64 + r) * DM + bx * 64 + cg + 8 * i];
    __syncthreads();
#pragma unroll
    for (int i = 0; i < 2; ++i) {
        bf16x8 o;
#pragma unroll
        for (int j = 0; j < 8; ++j) o[j] = tile[cg + 8 * i + j][r];
        *(bf16x8*)&vt[(size_t)(bx * 64 + r) * TT + by * 64 + cg + 8 * i] = o;
    }
}

// ---------------------------------------------------------------------------
// MFMA flash attention (round-4 proven): XCD swizzle, exp2 folded scale,
// MFMA ones-row row-sum.  + s_setprio(1) around MFMA clusters (T5: 4
// independent blocks/CU at different phases -> scheduler can favor the
// MFMA-issuing wave; m191 regime, not m190's lockstep-GEMM null).
// LDS = 38656 B -> 4 blocks/CU.
// ---------------------------------------------------------------------------
template <int MODE>   // 0 direct, 1 bf16 partials
__global__ __launch_bounds__(256) void attn_mfma(const bf16* __restrict__ qb,
                                                 const bf16* __restrict__ kb,
                                                 const bf16* __restrict__ vtb,
                                                 bf16* __restrict__ ob,
                                                 bf16* __restrict__ Opb,
                                                 float* __restrict__ Lp,
                                                 int kspan) {
    __shared__ __align__(16) __bf16 Ks[64][104];    // 13312 B
    __shared__ __align__(16) __bf16 Vts[112][72];   // 16128 B (row 96 = ones)
    __shared__ __align__(16) __bf16 Ps[4][16][72];  //  9216 B

    const int t = threadIdx.x;
    const int w = t >> 6, lane = t & 63;
    const int quad = lane >> 4, l15 = lane & 15;

    const int lid = blockIdx.x;
    const int xcd = lid & 7;
    const int s = lid >> 3;
    const int per = gridDim.x / 288;            // combos per XCD
    const int combo = xcd * per + s / 36;
    const int h = combo % NH;
    const int p = combo / NH;
    const int q0 = (s % 36) * 64;
    const int kstart = p * kspan;
    const float scale = 0.10206207261596575f * 1.4426950408889634f;  // /sqrt(96)*log2e

    bf16x8 qf[3];
#pragma unroll
    for (int ks = 0; ks < 3; ++ks) {
        qf[ks] = *(const bf16x8*)&qb[(size_t)(q0 + 16 * w + l15) * DM + h * DKH + quad * 8 + 32 * ks];
#pragma unroll
        for (int j = 0; j < 8; ++j) qf[ks][j] = (__bf16)((float)qf[ks][j] * scale);
    }

    const f32x4 fz = {0.f, 0.f, 0.f, 0.f};
    f32x4 Oa[6];
#pragma unroll
    for (int i = 0; i < 6; ++i) Oa[i] = fz;
    f32x4 Lacc = fz;
    float lrow[4] = {0.f, 0.f, 0.f, 0.f};

    if (MODE == 1 && t < 8) {
        bf16x8 one;
#pragma unroll
        for (int e = 0; e < 8; ++e) one[e] = (__bf16)1.0f;
        *(bf16x8*)&Vts[96][t * 8] = one;
    }

    bf16x8 kreg[3], vreg[3];
#pragma unroll
    for (int i = 0; i < 3; ++i) {
        const int idx = t + 256 * i;
        const int r = idx / 12, c = idx % 12;
        kreg[i] = *(const bf16x8*)&kb[(size_t)(kstart + r) * DM + h * DKH + c * 8];
        const int d = idx >> 3, ck = idx & 7;
        vreg[i] = *(const bf16x8*)&vtb[(size_t)(h * DKH + d) * TT + kstart + ck * 8];
    }

    for (int kc = kstart; kc < kstart + kspan; kc += 64) {
        __syncthreads();
#pragma unroll
        for (int i = 0; i < 3; ++i) {
            const int idx = t + 256 * i;
            const int r = idx / 12, c = idx % 12;
            *(bf16x8*)&Ks[r][c * 8] = kreg[i];
            const int d = idx >> 3, ck = idx & 7;
            *(bf16x8*)&Vts[d][ck * 8] = vreg[i];
        }
        __syncthreads();

        if (kc + 64 < kstart + kspan) {
#pragma unroll
            for (int i = 0; i < 3; ++i) {
                const int idx = t + 256 * i;
                const int r = idx / 12, c = idx % 12;
                kreg[i] = *(const bf16x8*)&kb[(size_t)(kc + 64 + r) * DM + h * DKH + c * 8];
                const int d = idx >> 3, ck = idx & 7;
                vreg[i] = *(const bf16x8*)&vtb[(size_t)(h * DKH + d) * TT + kc + 64 + ck * 8];
            }
        }

        f32x4 Sa[4] = {fz, fz, fz, fz};
        __builtin_amdgcn_s_setprio(1);
#pragma unroll
        for (int nt = 0; nt < 4; ++nt)
#pragma unroll
            for (int ks = 0; ks < 3; ++ks) {
                const bf16x8 kf = *(const bf16x8*)&Ks[l15 + 16 * nt][quad * 8 + 32 * ks];
                Sa[nt] = __builtin_amdgcn_mfma_f32_16x16x32_bf16(qf[ks], kf, Sa[nt], 0, 0, 0);
            }
        __builtin_amdgcn_s_setprio(0);

#pragma unroll
        for (int r = 0; r < 4; ++r) {
            const float p0 = __builtin_amdgcn_exp2f(Sa[0][r]);
            const float p1 = __builtin_amdgcn_exp2f(Sa[1][r]);
            const float p2 = __builtin_amdgcn_exp2f(Sa[2][r]);
            const float p3 = __builtin_amdgcn_exp2f(Sa[3][r]);
            Ps[w][quad * 4 + r][l15]      = (__bf16)p0;
            Ps[w][quad * 4 + r][l15 + 16] = (__bf16)p1;
            Ps[w][quad * 4 + r][l15 + 32] = (__bf16)p2;
            Ps[w][quad * 4 + r][l15 + 48] = (__bf16)p3;
            if (MODE == 0) {
                float ps = p0 + p1 + p2 + p3;
                ps += __shfl_xor(ps, 1);
                ps += __shfl_xor(ps, 2);
                ps += __shfl_xor(ps, 4);
                ps += __shfl_xor(ps, 8);
                lrow[r] += ps;
            }
        }

        const bf16x8 pa0 = *(const bf16x8*)&Ps[w][l15][quad * 8];
        const bf16x8 pa1 = *(const bf16x8*)&Ps[w][l15][32 + quad * 8];

        __builtin_amdgcn_s_setprio(1);
#pragma unroll
        for (int nt = 0; nt < 6; ++nt) {
            const bf16x8 vf0 = *(const bf16x8*)&Vts[l15 + 16 * nt][quad * 8];
            const bf16x8 vf1 = *(const bf16x8*)&Vts[l15 + 16 * nt][32 + quad * 8];
            Oa[nt] = __builtin_amdgcn_mfma_f32_16x16x32_bf16(pa0, vf0, Oa[nt], 0, 0, 0);
            Oa[nt] = __builtin_amdgcn_mfma_f32_16x16x32_bf16(pa1, vf1, Oa[nt], 0, 0, 0);
        }
        if (MODE == 1) {
            const bf16x8 of0 = *(const bf16x8*)&Vts[96 + l15][quad * 8];
            const bf16x8 of1 = *(const bf16x8*)&Vts[96 + l15][32 + quad * 8];
            Lacc = __builtin_amdgcn_mfma_f32_16x16x32_bf16(pa0, of0, Lacc, 0, 0, 0);
            Lacc = __builtin_amdgcn_mfma_f32_16x16x32_bf16(pa1, of1, Lacc, 0, 0, 0);
        }
        __builtin_amdgcn_s_setprio(0);
    }

    if (MODE == 0) {
#pragma unroll
        for (int nt = 0; nt < 6; ++nt)
#pragma unroll
            for (int r = 0; r < 4; ++r) {
                const int row = q0 + 16 * w + quad * 4 + r;
                ob[(size_t)row * DM + h * DKH + 16 * nt + l15] = f2b(Oa[nt][r] / lrow[r]);
            }
    } else {
#pragma unroll
        for (int nt = 0; nt < 6; ++nt)
#pragma unroll
            for (int r = 0; r < 4; ++r) {
                const int row = q0 + 16 * w + quad * 4 + r;
                Opb[((size_t)p * TT + row) * DM + h * DKH + 16 * nt + l15] = f2b(Oa[nt][r]);
            }
        if (l15 == 0) {
#pragma unroll
            for (int r = 0; r < 4; ++r) {
                const int row = q0 + 16 * w + quad * 4 + r;
                Lp[((size_t)p * NH + h) * TT + row] = Lacc[r];
            }
        }
    }
}

// ---------------------------------------------------------------------------
// merge: 8 rows/block, bf16x8 vector loads.
// ---------------------------------------------------------------------------
__global__ __launch_bounds__(256) void attn_merge(const bf16* __restrict__ Opb,
                                                  const float* __restrict__ Lp,
                                                  bf16* __restrict__ ob) {
    __shared__ float Ls[8][NH];
    const int r0 = blockIdx.x * 8;
    const int t = threadIdx.x;
    if (t < 8 * NH) {
        const int rl = t >> 3, hh = t & 7;
        float L = 0.f;
#pragma unroll
        for (int p = 0; p < SP; ++p) L += Lp[((size_t)p * NH + hh) * TT + r0 + rl];
        Ls[rl][hh] = 1.0f / L;
    }
    __syncthreads();
    const int rl = t >> 5, lane = t & 31;
    const int row = r0 + rl;
#pragma unroll
    for (int j = 0; j < 3; ++j) {
        const int d0 = lane * 8 + j * 256;
        float acc[8];
#pragma unroll
        for (int e = 0; e < 8; ++e) acc[e] = 0.f;
#pragma unroll
        for (int p = 0; p < SP; ++p) {
            const bf16x8 vv = *(const bf16x8*)&Opb[((size_t)p * TT + row) * DM + d0];
#pragma unroll
            for (int e = 0; e < 8; ++e) acc[e] += (float)vv[e];
        }
        const float s = Ls[rl][d0 / DKH];
        bf16x8 o;
#pragma unroll
        for (int e = 0; e < 8; ++e) o[e] = (__bf16)(acc[e] * s);
        *(bf16x8*)&ob[(size_t)row * DM + d0] = o;
    }
}

__global__ __launch_bounds__(256) void add_ln(bf16* __restrict__ x,
                                              const bf16* __restrict__ r,
                                              const float* __restrict__ g,
                                              const float* __restrict__ be) {
    __shared__ float red[4];
    const int row = blockIdx.x;
    bf16* xr = x + (size_t)row * DM;
    const bf16* rr = r + (size_t)row * DM;
    const int t = threadIdx.x;

    float v0 = b2f(xr[t]) + b2f(rr[t]);
    float v1 = b2f(xr[t + 256]) + b2f(rr[t + 256]);
    float v2 = b2f(xr[t + 512]) + b2f(rr[t + 512]);
    float s = v0 + v1 + v2;
#pragma unroll
    for (int off = 32; off >= 1; off >>= 1) s += __shfl_xor(s, off);
    if ((t & 63) == 0) red[t >> 6] = s;
    __syncthreads();
    s = red[0] + red[1] + red[2] + red[3];
    const float mean = s * (1.f / 768.f);
    __syncthreads();

    const float d0 = v0 - mean, d1 = v1 - mean, d2 = v2 - mean;
    float ss = d0 * d0 + d1 * d1 + d2 * d2;
#pragma unroll
    for (int off = 32; off >= 1; off >>= 1) ss += __shfl_xor(ss, off);
    if ((t & 63) == 0) red[t >> 6] = ss;
    __syncthreads();
    ss = red[0] + red[1] + red[2] + red[3];
    const float inv = rsqrtf(ss * (1.f / 768.f) + LN_EPS);

    xr[t]       = f2b(d0 * inv * g[t]       + be[t]);
    xr[t + 256] = f2b(d1 * inv * g[t + 256] + be[t + 256]);
    xr[t + 512] = f2b(d2 * inv * g[t + 512] + be[t + 512]);
}

__global__ __launch_bounds__(256) void predict(const bf16* __restrict__ x,
                                               const float* __restrict__ ng,
                                               const float* __restrict__ nb,
                                               const float* __restrict__ Wp,
                                               const float* __restrict__ bp,
                                               float* __restrict__ out) {
    __shared__ float xs[BAG][DM];
    __shared__ float red[4][BAG];
    const int t = threadIdx.x;
    const int rel = blockIdx.x;
    const int wid = t >> 6, lane = t & 63;

    for (int rep = 0; rep < 2; ++rep) {
        const int b = wid + rep * 4;
        const bf16* row = x + (size_t)(294 * b + 1) * DM;
        float vals[12];
        float s = 0.f;
#pragma unroll
        for (int i = 0; i < 12; ++i) { vals[i] = b2f(row[lane + i * 64]); s += vals[i]; }
#pragma unroll
        for (int off = 32; off >= 1; off >>= 1) s += __shfl_xor(s, off);
        const float mean = s * (1.f / 768.f);
        float ss = 0.f;
#pragma unroll
        for (int i = 0; i < 12; ++i) { const float d = vals[i] - mean; ss += d * d; }
#pragma unroll
        for (int off = 32; off >= 1; off >>= 1) ss += __shfl_xor(ss, off);
        const float inv = rsqrtf(ss * (1.f / 768.f) + LN_EPS);
#pragma unroll
        for (int i = 0; i < 12; ++i) {
            const int d = lane + i * 64;
            xs[b][d] = (vals[i] - mean) * inv * ng[d] + nb[d];
        }
    }
    __syncthreads();

    float pb[BAG];
#pragma unroll
    for (int b = 0; b < BAG; ++b) pb[b] = 0.f;
    for (int k = t; k < DM; k += 256) {
        const float wv = Wp[(size_t)k * NREL + rel];
#pragma unroll
        for (int b = 0; b < BAG; ++b) pb[b] += xs[b][k] * wv;
    }
#pragma unroll
    for (int b = 0; b < BAG; ++b)
#pragma unroll
        for (int off = 32; off >= 1; off >>= 1) pb[b] += __shfl_xor(pb[b], off);
    if (lane == 0)
#pragma unroll
        for (int b = 0; b < BAG; ++b) red[wid][b] = pb[b];
    __syncthreads();
    if (t == 0) {
        float mx = -3.0e38f;
        for (int b = 0; b < BAG; ++b) {
            const float v = red[0][b] + red[1][b] + red[2][b] + red[3][b] + bp[rel];
            out[NREL + b * NREL + rel] = v;
            mx = fmaxf(mx, v);
        }
        out[rel] = mx;
    }
}

// ---------------------------------------------------------------------------
// host. ws layout (bytes), high-water 48,635,904:
//   htb 0 | u2 73728 (48x1536 fused u|v) | x 221184 | Bq 3760128
//   Bk 7299072 | Bv 10838016 | Vt 15556608 | slab 19095552 | Opb 26959872
//   (SP=6 bf16, 21.2 MB) | Lp 48193536
// ---------------------------------------------------------------------------
extern "C" void kernel_launch(void* const* d_in, const int* in_sizes, int n_in,
                              void* d_out, int out_size, void* d_ws, size_t ws_size,
                              hipStream_t stream) {
    const float* emb  = (const float*)d_in[0];
    const int* spans  = (const int*)d_in[1];
    const float* Wu = (const float*)d_in[2];  const float* bu = (const float*)d_in[3];
    const float* Wv = (const float*)d_in[4];  const float* bv = (const float*)d_in[5];
    const float* Wl = (const float*)d_in[6];  const float* bl = (const float*)d_in[7];
    const float* Wq = (const float*)d_in[8];  const float* bq = (const float*)d_in[9];
    const float* Wk = (const float*)d_in[10]; const float* bk = (const float*)d_in[11];
    const float* Wvm = (const float*)d_in[12]; const float* bvm = (const float*)d_in[13];
    const float* Wo = (const float*)d_in[14]; const float* bo = (const float*)d_in[15];
    const float* F1 = (const float*)d_in[16]; const float* f1 = (const float*)d_in[17];
    const float* F2 = (const float*)d_in[18]; const float* f2 = (const float*)d_in[19];
    const float* g1 = (const float*)d_in[20]; const float* be1 = (const float*)d_in[21];
    const float* g2 = (const float*)d_in[22]; const float* be2 = (const float*)d_in[23];
    const float* ng = (const float*)d_in[24]; const float* nb = (const float*)d_in[25];
    const float* Wp = (const float*)d_in[26]; const float* bp = (const float*)d_in[27];

    char* wsb = (char*)d_ws;
    bf16* htb = (bf16*)(wsb + 0);
    bf16* u2  = (bf16*)(wsb + 73728);     // full path: 48x1536 fused u|v
    bf16* ub  = (bf16*)(wsb + 73728);     // fallback: 48x768
    bf16* vbn = (bf16*)(wsb + 147456);    // fallback: 48x768
    bf16* x   = (bf16*)(wsb + 221184);
    bf16* Bq  = (bf16*)(wsb + 3760128);
    bf16* Bk  = (bf16*)(wsb + 7299072);
    bf16* Bv  = (bf16*)(wsb + 10838016);
    bf16* Vt  = (bf16*)(wsb + 15556608);
    bf16* slab = (bf16*)(wsb + 19095552);
    bf16* Opb = (bf16*)(wsb + 26959872);
    float* Lp = (float*)(wsb + 48193536);

    const size_t FULL_END = 48635904;
    const bool use_full = ws_size >= FULL_END;

    span_pool<<<dim3(NNODE, 6), 128, 0, stream>>>(emb, spans, htb);

    if (use_full) {
        prep_wt3<<<dim3(12, 12, 3), 256, 0, stream>>>(Wu, Wv, Wl, slab);
        // fused u|v GEMM: Bt = [Wu^T ; Wv^T] contiguous in slab, N=1536
        gemm_bt256<0, 1><<<dim3(24, 1), 256, 0, stream>>>(htb, slab, bu, bv, u2,
                                                          NNODE, 2 * DM, DM);
        // rel GEMM with fused relu(u_i+v_j) A-staging
        gemm_rel<<<dim3(12, TT / 64), 256, 0, stream>>>(u2, slab + 1179648, bl, x);

        for (int l = 0; l < NLAYER; ++l) {
            const size_t wo = (size_t)l * DM * DM;
            const size_t f1o = (size_t)l * DM * DFF;
            prep6<<<dim3(16, 16, 6), 256, 0, stream>>>(Wq + wo, Wk + wo, Wvm + wo,
                                                       Wo + wo, F1 + f1o, F2 + f1o, slab);
            gemm_qkv256<<<dim3(36, TT / 64), 256, 0, stream>>>(x, slab, bq + l * DM, bk + l * DM,
                                                               bvm + l * DM, Bq, Bk, Vt);
            attn_mfma<1><<<dim3(36 * NH * SP), 256, 0, stream>>>(Bq, Bk, Vt, Bq, Opb, Lp, KSPAN);
            attn_merge<<<TT / 8, 256, 0, stream>>>(Opb, Lp, Bq);
            gemm_bt256<0, 0><<<dim3(12, TT / 64), 256, 0, stream>>>(Bq, slab + 1769472, bo + l * DM,
                                                                    bo + l * DM, Bk, TT, DM, DM);
            add_ln<<<TT, 256, 0, stream>>>(x, Bk, g1 + l * DM, be1 + l * DM);
            gemm_bt256<1, 0><<<dim3(16, TT / 64), 256, 0, stream>>>(x, slab + 2359296, f1 + l * DFF,
                                                                    f1 + l * DFF, Bv, TT, DFF, DM);
            gemm_bt256<0, 0><<<dim3(12, TT / 64), 256, 0, stream>>>(Bv, slab + 3145728, f2 + l * DM,
                                                                    f2 + l * DM, Bk, TT, DM, DFF);
            add_ln<<<TT, 256, 0, stream>>>(x, Bk, g2 + l * DM, be2 + l * DM);
        }
    } else {
        gemm_mfma<0><<<dim3(12, 2), 128, 0, stream>>>(htb, Wu, bu, ub, NNODE, DM, DM);
        gemm_mfma<0><<<dim3(12, 2), 128, 0, stream>>>(htb, Wv, bv, vbn, NNODE, DM, DM);
        build_relA<<<TT, 256, 0, stream>>>(ub, vbn, DM, Bq);
        gemm_mfma<1><<<dim3(12, TT / 32), 128, 0, stream>>>(Bq, Wl, bl, x, TT, DM, DM);

        for (int l = 0; l < NLAYER; ++l) {
            const size_t wo = (size_t)l * DM * DM;
            const size_t f1o = (size_t)l * DM * DFF;
            gemm_mfma<0><<<dim3(12, TT / 32), 128, 0, stream>>>(x, Wq + wo, bq + l * DM, Bq, TT, DM, DM);
            gemm_mfma<0><<<dim3(12, TT / 32), 128, 0, stream>>>(x, Wk + wo, bk + l * DM, Bk, TT, DM, DM);
            gemm_mfma<0><<<dim3(12, TT / 32), 128, 0, stream>>>(x, Wvm + wo, bvm + l * DM, Bv, TT, DM, DM);
            transpose_v<<<dim3(DM / 64, TT / 64), 256, 0, stream>>>(Bv, Vt);
            attn_mfma<0><<<dim3(36 * NH), 256, 0, stream>>>(Bq, Bk, Vt, Bq, Opb, Lp, TT);
            gemm_mfma<0><<<dim3(12, TT / 32), 128, 0, stream>>>(Bq, Wo + wo, bo + l * DM, Bk, TT, DM, DM);
            add_ln<<<TT, 256, 0, stream>>>(x, Bk, g1 + l * DM, be1 + l * DM);
            gemm_mfma<1><<<dim3(16, TT / 32), 128, 0, stream>>>(x, F1 + f1o, f1 + l * DFF, Bv, TT, DFF, DM);
            gemm_mfma<0><<<dim3(12, TT / 32), 128, 0, stream>>>(Bv, F2 + f1o, f2 + l * DM, Bk, TT, DM, DFF);
            add_ln<<<TT, 256, 0, stream>>>(x, Bk, g2 + l * DM, be2 + l * DM);
        }
    }

    predict<<<NREL, 256, 0, stream>>>(x, ng, nb, Wp, bp, (float*)d_out);
}

// Round 7
// 625.134 us; speedup vs baseline: 1.0619x; 1.0092x over previous
//
#include <hip/hip_runtime.h>
#include <hip/hip_bf16.h>

typedef __hip_bfloat16 bf16;
typedef __bf16 bf16x8 __attribute__((ext_vector_type(8)));
typedef float f32x4 __attribute__((ext_vector_type(4)));

#define BAG 8
#define SEQ 512
#define DM 768
#define NPD 6
#define NNODE 48
#define TT 2304
#define NH 8
#define DKH 96
#define DFF 1024
#define NLAYER 4
#define NREL 97
#define SP 6
#define KSPAN (TT / SP)
#define LN_EPS 1e-5f

__device__ __forceinline__ float b2f(const bf16 x) { return __bfloat162float(x); }
__device__ __forceinline__ bf16 f2b(float f) { return __float2bfloat16(f); }
__device__ __forceinline__ unsigned short f2bu(float f) {
    bf16 h = __float2bfloat16(f);
    return *reinterpret_cast<unsigned short*>(&h);
}

__global__ __launch_bounds__(128) void span_pool(const float* __restrict__ emb,
                                                 const int* __restrict__ spans,
                                                 bf16* __restrict__ htb) {
    const int n = blockIdx.x;
    const int b = n / NPD;
    int s0 = spans[n * 2 + 0];
    int s1 = spans[n * 2 + 1];
    s0 = min(max(s0, 0), SEQ - 1);
    s1 = min(max(s1, s0), SEQ - 1);
    const float* base = emb + (size_t)b * SEQ * DM;
    const int d = blockIdx.y * 128 + threadIdx.x;
    float m = -3.0e38f;
    for (int s = s0; s <= s1; ++s) m = fmaxf(m, base[(size_t)s * DM + d]);
    htb[(size_t)n * DM + d] = f2b(m);
}

// ---------------------------------------------------------------------------
// weight prep (3 DMxDM): W[K][N] f32 -> Wt[N][K] bf16, out at z*DM*DM
// ---------------------------------------------------------------------------
__global__ __launch_bounds__(256) void prep_wt3(const float* __restrict__ W0,
                                                const float* __restrict__ W1,
                                                const float* __restrict__ W2,
                                                bf16* __restrict__ Wt) {
    __shared__ __align__(16) __bf16 tile[64][72];
    const int z = blockIdx.z;
    const float* W = (z == 0) ? W0 : (z == 1) ? W1 : W2;
    bf16* out = Wt + (size_t)z * DM * DM;
    const int t = threadIdx.x;
    const int k0 = blockIdx.x * 64, n0 = blockIdx.y * 64;
    const int r = t >> 2, cg = (t & 3) * 16;
#pragma unroll
    for (int i = 0; i < 4; ++i) {
        const float4 v = *(const float4*)&W[(size_t)(k0 + r) * DM + n0 + cg + 4 * i];
        tile[r][cg + 4 * i + 0] = (__bf16)v.x;
        tile[r][cg + 4 * i + 1] = (__bf16)v.y;
        tile[r][cg + 4 * i + 2] = (__bf16)v.z;
        tile[r][cg + 4 * i + 3] = (__bf16)v.w;
    }
    __syncthreads();
#pragma unroll
    for (int i = 0; i < 2; ++i) {
        bf16x8 o;
#pragma unroll
        for (int j = 0; j < 8; ++j) o[j] = tile[cg + 8 * i + j][r];
        *(bf16x8*)&out[(size_t)(n0 + r) * DM + k0 + cg + 8 * i] = o;
    }
}

// ---------------------------------------------------------------------------
// prep6: one launch converts Wq,Wk,Wv,Wo,F1,F2 -> transposed bf16 slab.
// ---------------------------------------------------------------------------
__global__ __launch_bounds__(256) void prep6(const float* __restrict__ Wq,
                                             const float* __restrict__ Wk,
                                             const float* __restrict__ Wv,
                                             const float* __restrict__ Wo,
                                             const float* __restrict__ F1,
                                             const float* __restrict__ F2,
                                             bf16* __restrict__ slab) {
    __shared__ __align__(16) __bf16 tile[64][72];
    const int z = blockIdx.z;
    int K = DM, N = DM;
    const float* W;
    size_t off;
    switch (z) {
        case 0: W = Wq; off = 0;       break;
        case 1: W = Wk; off = 589824;  break;
        case 2: W = Wv; off = 1179648; break;
        case 3: W = Wo; off = 1769472; break;
        case 4: W = F1; off = 2359296; N = DFF; break;
        default: W = F2; off = 3145728; K = DFF; break;
    }
    const int k0 = blockIdx.x * 64, n0 = blockIdx.y * 64;
    if (k0 >= K || n0 >= N) return;
    bf16* out = slab + off;
    const int t = threadIdx.x;
    const int r = t >> 2, cg = (t & 3) * 16;
#pragma unroll
    for (int i = 0; i < 4; ++i) {
        const float4 v = *(const float4*)&W[(size_t)(k0 + r) * N + n0 + cg + 4 * i];
        tile[r][cg + 4 * i + 0] = (__bf16)v.x;
        tile[r][cg + 4 * i + 1] = (__bf16)v.y;
        tile[r][cg + 4 * i + 2] = (__bf16)v.z;
        tile[r][cg + 4 * i + 3] = (__bf16)v.w;
    }
    __syncthreads();
#pragma unroll
    for (int i = 0; i < 2; ++i) {
        bf16x8 o;
#pragma unroll
        for (int j = 0; j < 8; ++j) o[j] = tile[cg + 8 * i + j][r];
        *(bf16x8*)&out[(size_t)(n0 + r) * K + k0 + cg + 8 * i] = o;
    }
}

// ---------------------------------------------------------------------------
// MFMA GEMM v3: 64x64 tile, 256 threads = 4 waves in 2x2 grid, BK=64,
// double-buffered LDS (36864 B -> 4 blocks/CU), one barrier per K-iter.
// Used for grids <= 1024 blocks (no residency tail at 4 blocks/CU).
// DUAL=1: bias is split [bias | bias2] at col DM (for fused u/v GEMM).
// ---------------------------------------------------------------------------
template <int RELU, int DUAL>
__global__ __launch_bounds__(256) void gemm_bt256(const bf16* __restrict__ A,
                                                  const bf16* __restrict__ Bt,
                                                  const float* __restrict__ bias,
                                                  const float* __restrict__ bias2,
                                                  bf16* __restrict__ C,
                                                  int M, int N, int K) {
    __shared__ __align__(16) __bf16 As[2][64][72];
    __shared__ __align__(16) __bf16 Bs[2][64][72];
    const int t = threadIdx.x;
    const int w = t >> 6, lane = t & 63;
    const int quad = lane >> 4, l15 = lane & 15;
    const int wr = w >> 1, wc = w & 1;            // 2x2 wave grid
    const int row0 = blockIdx.y * 64, col0 = blockIdx.x * 64;
    const int s_row = t >> 2, s_off = (t & 3) * 16;
    const bool a_ok = (row0 + s_row) < M;

    const f32x4 fz = {0.f, 0.f, 0.f, 0.f};
    f32x4 acc[2][2];
#pragma unroll
    for (int m = 0; m < 2; ++m)
#pragma unroll
        for (int n = 0; n < 2; ++n) acc[m][n] = fz;

    bf16x8 av[2], bv[2];
#pragma unroll
    for (int j = 0; j < 2; ++j)
#pragma unroll
        for (int e = 0; e < 8; ++e) av[j][e] = (__bf16)0.0f;
    if (a_ok)
#pragma unroll
        for (int j = 0; j < 2; ++j)
            av[j] = *(const bf16x8*)&A[(size_t)(row0 + s_row) * K + s_off + 8 * j];
#pragma unroll
    for (int j = 0; j < 2; ++j)
        bv[j] = *(const bf16x8*)&Bt[(size_t)(col0 + s_row) * K + s_off + 8 * j];

    int cur = 0;
    for (int k0 = 0; k0 < K; k0 += 64) {
#pragma unroll
        for (int j = 0; j < 2; ++j) {
            *(bf16x8*)&As[cur][s_row][s_off + 8 * j] = av[j];
            *(bf16x8*)&Bs[cur][s_row][s_off + 8 * j] = bv[j];
        }
        __syncthreads();

        if (k0 + 64 < K) {
            if (a_ok)
#pragma unroll
                for (int j = 0; j < 2; ++j)
                    av[j] = *(const bf16x8*)&A[(size_t)(row0 + s_row) * K + k0 + 64 + s_off + 8 * j];
#pragma unroll
            for (int j = 0; j < 2; ++j)
                bv[j] = *(const bf16x8*)&Bt[(size_t)(col0 + s_row) * K + k0 + 64 + s_off + 8 * j];
        }

#pragma unroll
        for (int kk = 0; kk < 2; ++kk) {
            const bf16x8 af0 = *(const bf16x8*)&As[cur][wr * 32 + l15][quad * 8 + 32 * kk];
            const bf16x8 af1 = *(const bf16x8*)&As[cur][wr * 32 + 16 + l15][quad * 8 + 32 * kk];
            const bf16x8 bf0 = *(const bf16x8*)&Bs[cur][wc * 32 + l15][quad * 8 + 32 * kk];
            const bf16x8 bf1 = *(const bf16x8*)&Bs[cur][wc * 32 + 16 + l15][quad * 8 + 32 * kk];
            acc[0][0] = __builtin_amdgcn_mfma_f32_16x16x32_bf16(af0, bf0, acc[0][0], 0, 0, 0);
            acc[0][1] = __builtin_amdgcn_mfma_f32_16x16x32_bf16(af0, bf1, acc[0][1], 0, 0, 0);
            acc[1][0] = __builtin_amdgcn_mfma_f32_16x16x32_bf16(af1, bf0, acc[1][0], 0, 0, 0);
            acc[1][1] = __builtin_amdgcn_mfma_f32_16x16x32_bf16(af1, bf1, acc[1][1], 0, 0, 0);
        }
        cur ^= 1;
    }

#pragma unroll
    for (int n = 0; n < 2; ++n) {
        const int col = col0 + wc * 32 + 16 * n + l15;
        const float bvl = (DUAL && col >= DM) ? bias2[col - DM] : bias[col];
#pragma unroll
        for (int m = 0; m < 2; ++m)
#pragma unroll
            for (int r = 0; r < 4; ++r) {
                const int row = row0 + wr * 32 + 16 * m + quad * 4 + r;
                if (row < M) {
                    float v = acc[m][n][r] + bvl;
                    if (RELU) v = fmaxf(v, 0.f);
                    C[(size_t)row * N + col] = f2b(v);
                }
            }
    }
}

// ---------------------------------------------------------------------------
// gemm_rel: rel GEMM with build_relA FUSED into A-staging:
// A[cell][k] = relu(u2[i][k] + u2[j][768+k]), cell = i*48+j.
// ---------------------------------------------------------------------------
__global__ __launch_bounds__(256) void gemm_rel(const bf16* __restrict__ u2,
                                                const bf16* __restrict__ Bt,
                                                const float* __restrict__ bias,
                                                bf16* __restrict__ C) {
    __shared__ __align__(16) __bf16 As[2][64][72];
    __shared__ __align__(16) __bf16 Bs[2][64][72];
    const int t = threadIdx.x;
    const int w = t >> 6, lane = t & 63;
    const int quad = lane >> 4, l15 = lane & 15;
    const int wr = w >> 1, wc = w & 1;
    const int row0 = blockIdx.y * 64, col0 = blockIdx.x * 64;
    const int s_row = t >> 2, s_off = (t & 3) * 16;
    const int cell = row0 + s_row;
    const bf16* up = u2 + (size_t)(cell / NNODE) * (2 * DM);
    const bf16* vp = u2 + (size_t)(cell % NNODE) * (2 * DM) + DM;

    const f32x4 fz = {0.f, 0.f, 0.f, 0.f};
    f32x4 acc[2][2];
#pragma unroll
    for (int m = 0; m < 2; ++m)
#pragma unroll
        for (int n = 0; n < 2; ++n) acc[m][n] = fz;

    bf16x8 uu[2], vv[2], bv[2];
#pragma unroll
    for (int j = 0; j < 2; ++j) {
        uu[j] = *(const bf16x8*)&up[s_off + 8 * j];
        vv[j] = *(const bf16x8*)&vp[s_off + 8 * j];
        bv[j] = *(const bf16x8*)&Bt[(size_t)(col0 + s_row) * DM + s_off + 8 * j];
    }

    int cur = 0;
    for (int k0 = 0; k0 < DM; k0 += 64) {
#pragma unroll
        for (int j = 0; j < 2; ++j) {
            bf16x8 o;
#pragma unroll
            for (int e = 0; e < 8; ++e)
                o[e] = (__bf16)fmaxf((float)uu[j][e] + (float)vv[j][e], 0.f);
            *(bf16x8*)&As[cur][s_row][s_off + 8 * j] = o;
            *(bf16x8*)&Bs[cur][s_row][s_off + 8 * j] = bv[j];
        }
        __syncthreads();

        if (k0 + 64 < DM) {
#pragma unroll
            for (int j = 0; j < 2; ++j) {
                uu[j] = *(const bf16x8*)&up[k0 + 64 + s_off + 8 * j];
                vv[j] = *(const bf16x8*)&vp[k0 + 64 + s_off + 8 * j];
                bv[j] = *(const bf16x8*)&Bt[(size_t)(col0 + s_row) * DM + k0 + 64 + s_off + 8 * j];
            }
        }

#pragma unroll
        for (int kk = 0; kk < 2; ++kk) {
            const bf16x8 af0 = *(const bf16x8*)&As[cur][wr * 32 + l15][quad * 8 + 32 * kk];
            const bf16x8 af1 = *(const bf16x8*)&As[cur][wr * 32 + 16 + l15][quad * 8 + 32 * kk];
            const bf16x8 bf0 = *(const bf16x8*)&Bs[cur][wc * 32 + l15][quad * 8 + 32 * kk];
            const bf16x8 bf1 = *(const bf16x8*)&Bs[cur][wc * 32 + 16 + l15][quad * 8 + 32 * kk];
            acc[0][0] = __builtin_amdgcn_mfma_f32_16x16x32_bf16(af0, bf0, acc[0][0], 0, 0, 0);
            acc[0][1] = __builtin_amdgcn_mfma_f32_16x16x32_bf16(af0, bf1, acc[0][1], 0, 0, 0);
            acc[1][0] = __builtin_amdgcn_mfma_f32_16x16x32_bf16(af1, bf0, acc[1][0], 0, 0, 0);
            acc[1][1] = __builtin_amdgcn_mfma_f32_16x16x32_bf16(af1, bf1, acc[1][1], 0, 0, 0);
        }
        cur ^= 1;
    }

#pragma unroll
    for (int n = 0; n < 2; ++n) {
        const int col = col0 + wc * 32 + 16 * n + l15;
        const float bvl = bias[col];
#pragma unroll
        for (int m = 0; m < 2; ++m)
#pragma unroll
            for (int r = 0; r < 4; ++r) {
                const int row = row0 + wr * 32 + 16 * m + quad * 4 + r;
                C[(size_t)row * DM + col] = f2b(fmaxf(acc[m][n][r] + bvl, 0.f));
            }
    }
}

// ---------------------------------------------------------------------------
// fused QKV GEMM: 64x64 tile, 256 threads, SINGLE-buffered LDS (18432 B ->
// 8 blocks/CU) so all 1296 blocks are co-resident (kills the 4-block/CU
// residency tail: 1296 > 1024). Two barriers/iter, hidden by ~20 waves/CU.
// V tiles (col0 >= 2*DM) written TRANSPOSED to Vt[768][TT] via LDS bounce.
// ---------------------------------------------------------------------------
__global__ __launch_bounds__(256) void gemm_qkv256(const bf16* __restrict__ A,
                                                   const bf16* __restrict__ Bt,
                                                   const float* __restrict__ b0,
                                                   const float* __restrict__ b1,
                                                   const float* __restrict__ b2,
                                                   bf16* __restrict__ C0,
                                                   bf16* __restrict__ C1,
                                                   bf16* __restrict__ Vt) {
    __shared__ __align__(16) __bf16 As[64][72];
    __shared__ __align__(16) __bf16 Bs[64][72];
    const int t = threadIdx.x;
    const int w = t >> 6, lane = t & 63;
    const int quad = lane >> 4, l15 = lane & 15;
    const int wr = w >> 1, wc = w & 1;
    const int row0 = blockIdx.y * 64, col0 = blockIdx.x * 64;
    const int s_row = t >> 2, s_off = (t & 3) * 16;

    const f32x4 fz = {0.f, 0.f, 0.f, 0.f};
    f32x4 acc[2][2];
#pragma unroll
    for (int m = 0; m < 2; ++m)
#pragma unroll
        for (int n = 0; n < 2; ++n) acc[m][n] = fz;

    bf16x8 av[2], bv[2];
#pragma unroll
    for (int j = 0; j < 2; ++j) {
        av[j] = *(const bf16x8*)&A[(size_t)(row0 + s_row) * DM + s_off + 8 * j];
        bv[j] = *(const bf16x8*)&Bt[(size_t)(col0 + s_row) * DM + s_off + 8 * j];
    }

    for (int k0 = 0; k0 < DM; k0 += 64) {
#pragma unroll
        for (int j = 0; j < 2; ++j) {
            *(bf16x8*)&As[s_row][s_off + 8 * j] = av[j];
            *(bf16x8*)&Bs[s_row][s_off + 8 * j] = bv[j];
        }
        __syncthreads();

        if (k0 + 64 < DM) {
#pragma unroll
            for (int j = 0; j < 2; ++j) {
                av[j] = *(const bf16x8*)&A[(size_t)(row0 + s_row) * DM + k0 + 64 + s_off + 8 * j];
                bv[j] = *(const bf16x8*)&Bt[(size_t)(col0 + s_row) * DM + k0 + 64 + s_off + 8 * j];
            }
        }

#pragma unroll
        for (int kk = 0; kk < 2; ++kk) {
            const bf16x8 af0 = *(const bf16x8*)&As[wr * 32 + l15][quad * 8 + 32 * kk];
            const bf16x8 af1 = *(const bf16x8*)&As[wr * 32 + 16 + l15][quad * 8 + 32 * kk];
            const bf16x8 bf0 = *(const bf16x8*)&Bs[wc * 32 + l15][quad * 8 + 32 * kk];
            const bf16x8 bf1 = *(const bf16x8*)&Bs[wc * 32 + 16 + l15][quad * 8 + 32 * kk];
            acc[0][0] = __builtin_amdgcn_mfma_f32_16x16x32_bf16(af0, bf0, acc[0][0], 0, 0, 0);
            acc[0][1] = __builtin_amdgcn_mfma_f32_16x16x32_bf16(af0, bf1, acc[0][1], 0, 0, 0);
            acc[1][0] = __builtin_amdgcn_mfma_f32_16x16x32_bf16(af1, bf0, acc[1][0], 0, 0, 0);
            acc[1][1] = __builtin_amdgcn_mfma_f32_16x16x32_bf16(af1, bf1, acc[1][1], 0, 0, 0);
        }
        __syncthreads();
    }

    const int buf = col0 / DM;
    const int lc0 = col0 - buf * DM;
    if (buf < 2) {
        bf16* Cb = (buf == 0) ? C0 : C1;
        const float* bb = (buf == 0) ? b0 : b1;
#pragma unroll
        for (int n = 0; n < 2; ++n) {
            const int col = lc0 + wc * 32 + 16 * n + l15;
            const float bvl = bb[col];
#pragma unroll
            for (int m = 0; m < 2; ++m)
#pragma unroll
                for (int r = 0; r < 4; ++r) {
                    const int row = row0 + wr * 32 + 16 * m + quad * 4 + r;
                    Cb[(size_t)row * DM + col] = f2b(acc[m][n][r] + bvl);
                }
        }
    } else {
        __bf16 (*Tb)[72] = As;   // [col_local][row_local]
#pragma unroll
        for (int n = 0; n < 2; ++n) {
            const int cl = wc * 32 + 16 * n + l15;
            const float bvl = b2[lc0 + cl];
#pragma unroll
            for (int m = 0; m < 2; ++m)
#pragma unroll
                for (int r = 0; r < 4; ++r)
                    Tb[cl][wr * 32 + 16 * m + quad * 4 + r] = (__bf16)(acc[m][n][r] + bvl);
        }
        __syncthreads();
        const int c = t >> 2, seg = (t & 3) * 16;
        const bf16x8 o0 = *(const bf16x8*)&Tb[c][seg];
        const bf16x8 o1 = *(const bf16x8*)&Tb[c][seg + 8];
        *(bf16x8*)&Vt[(size_t)(lc0 + c) * TT + row0 + seg] = o0;
        *(bf16x8*)&Vt[(size_t)(lc0 + c) * TT + row0 + seg + 8] = o1;
    }
}

// fallback GEMM (f32 weights, staging conversion)
template <int RELU>
__global__ __launch_bounds__(128) void gemm_mfma(const bf16* __restrict__ A,
                                                 const float* __restrict__ W,
                                                 const float* __restrict__ bias,
                                                 bf16* __restrict__ C,
                                                 int M, int N, int K) {
    __shared__ __align__(16) __bf16 As[32][40];
    __shared__ __align__(16) __bf16 Bs[64][40];
    const int t = threadIdx.x;
    const int w = t >> 6, lane = t & 63;
    const int quad = lane >> 4, l15 = lane & 15;
    const int row0 = blockIdx.y * 32, col0 = blockIdx.x * 64;
    const int s_row = t >> 2, s_kg = (t & 3) * 8;
    const int s_colg = (t & 15) * 4, s_kp = t >> 4;
    const bool a_ok = (row0 + s_row) < M;
    const f32x4 fz = {0.f, 0.f, 0.f, 0.f};
    f32x4 acc[4];
#pragma unroll
    for (int i = 0; i < 4; ++i) acc[i] = fz;

    for (int k0 = 0; k0 < K; k0 += 32) {
        bf16x8 av;
        for (int j = 0; j < 8; ++j) av[j] = (__bf16)0.0f;
        if (a_ok) av = *(const bf16x8*)&A[(size_t)(row0 + s_row) * K + k0 + s_kg];
        *(bf16x8*)&As[s_row][s_kg] = av;
#pragma unroll
        for (int rep = 0; rep < 2; ++rep) {
            const int kp = s_kp + 8 * rep;
            const size_t gb = (size_t)(k0 + 2 * kp) * N + col0 + s_colg;
            const float4 w0 = *(const float4*)&W[gb];
            const float4 w1 = *(const float4*)&W[gb + N];
#pragma unroll
            for (int i = 0; i < 4; ++i) {
                ushort2 pk;
                pk.x = f2bu((&w0.x)[i]);
                pk.y = f2bu((&w1.x)[i]);
                *(ushort2*)&Bs[s_colg + i][2 * kp] = pk;
            }
        }
        __syncthreads();
        const bf16x8 af = *(const bf16x8*)&As[16 * w + l15][quad * 8];
#pragma unroll
        for (int nt = 0; nt < 4; ++nt) {
            const bf16x8 bfv = *(const bf16x8*)&Bs[16 * nt + l15][quad * 8];
            acc[nt] = __builtin_amdgcn_mfma_f32_16x16x32_bf16(af, bfv, acc[nt], 0, 0, 0);
        }
        __syncthreads();
    }
#pragma unroll
    for (int nt = 0; nt < 4; ++nt) {
        const int col = col0 + 16 * nt + l15;
        const float bvl = bias[col];
#pragma unroll
        for (int r = 0; r < 4; ++r) {
            const int row = row0 + 16 * w + quad * 4 + r;
            if (row < M) {
                float v = acc[nt][r] + bvl;
                if (RELU) v = fmaxf(v, 0.f);
                C[(size_t)row * N + col] = f2b(v);
            }
        }
    }
}

// build_relA (fallback path only)
__global__ __launch_bounds__(256) void build_relA(const bf16* __restrict__ u,
                                                  const bf16* __restrict__ v,
                                                  int stride,
                                                  bf16* __restrict__ A) {
    const int cell = blockIdx.x;
    const int i = cell / NNODE, j = cell % NNODE;
    for (int k = threadIdx.x; k < DM; k += 256) {
        A[(size_t)cell * DM + k] =
            f2b(fmaxf(b2f(u[(size_t)i * stride + k]) + b2f(v[(size_t)j * stride + k]), 0.f));
    }
}

__global__ __launch_bounds__(256) void transpose_v(const bf16* __restrict__ v,
                                                   bf16* __restrict__ vt) {
    __shared__ __align__(16) __bf16 tile[64][72];
    const int t = threadIdx.x;
    const int bx = blockIdx.x, by = blockIdx.y;
    const int r = t >> 2, cg = (t & 3) * 16;
#pragma unroll
    for (int i = 0; i < 2; ++i)
        *(bf16x8*)&tile[r][cg + 8 * i] =
            *(const bf16x8*)&v[(size_t)(by * 64 + r) * DM + bx * 64 + cg + 8 * i];
    __syncthreads();
#pragma unroll
    for (int i = 0; i < 2; ++i) {
        bf16x8 o;
#pragma unroll
        for (int j = 0; j < 8; ++j) o[j] = tile[cg + 8 * i + j][r];
        *(bf16x8*)&vt[(size_t)(bx * 64 + r) * TT + by * 64 + cg + 8 * i] = o;
    }
}

// ---------------------------------------------------------------------------
// MFMA flash attention (round-6 proven + compile-time kspan): XCD swizzle,
// exp2 folded scale, MFMA ones-row row-sum, setprio around MFMA clusters.
// KSP as template constant lets the compiler fully unroll the 6-iter K-loop
// (hoists idx/12 chains, schedules prefetch across iterations).
// LDS = 38656 B -> 4 blocks/CU.
// ---------------------------------------------------------------------------
template <int MODE, int KSP>   // MODE: 0 direct, 1 bf16 partials
__global__ __launch_bounds__(256) void attn_mfma(const bf16* __restrict__ qb,
                                                 const bf16* __restrict__ kb,
                                                 const bf16* __restrict__ vtb,
                                                 bf16* __restrict__ ob,
                                                 bf16* __restrict__ Opb,
                                                 float* __restrict__ Lp) {
    __shared__ __align__(16) __bf16 Ks[64][104];    // 13312 B
    __shared__ __align__(16) __bf16 Vts[112][72];   // 16128 B (row 96 = ones)
    __shared__ __align__(16) __bf16 Ps[4][16][72];  //  9216 B

    const int t = threadIdx.x;
    const int w = t >> 6, lane = t & 63;
    const int quad = lane >> 4, l15 = lane & 15;

    const int lid = blockIdx.x;
    const int xcd = lid & 7;
    const int s = lid >> 3;
    const int per = gridDim.x / 288;            // combos per XCD
    const int combo = xcd * per + s / 36;
    const int h = combo % NH;
    const int p = combo / NH;
    const int q0 = (s % 36) * 64;
    const int kstart = p * KSP;
    const float scale = 0.10206207261596575f * 1.4426950408889634f;  // /sqrt(96)*log2e

    bf16x8 qf[3];
#pragma unroll
    for (int ks = 0; ks < 3; ++ks) {
        qf[ks] = *(const bf16x8*)&qb[(size_t)(q0 + 16 * w + l15) * DM + h * DKH + quad * 8 + 32 * ks];
#pragma unroll
        for (int j = 0; j < 8; ++j) qf[ks][j] = (__bf16)((float)qf[ks][j] * scale);
    }

    const f32x4 fz = {0.f, 0.f, 0.f, 0.f};
    f32x4 Oa[6];
#pragma unroll
    for (int i = 0; i < 6; ++i) Oa[i] = fz;
    f32x4 Lacc = fz;
    float lrow[4] = {0.f, 0.f, 0.f, 0.f};

    if (MODE == 1 && t < 8) {
        bf16x8 one;
#pragma unroll
        for (int e = 0; e < 8; ++e) one[e] = (__bf16)1.0f;
        *(bf16x8*)&Vts[96][t * 8] = one;
    }

    bf16x8 kreg[3], vreg[3];
#pragma unroll
    for (int i = 0; i < 3; ++i) {
        const int idx = t + 256 * i;
        const int r = idx / 12, c = idx % 12;
        kreg[i] = *(const bf16x8*)&kb[(size_t)(kstart + r) * DM + h * DKH + c * 8];
        const int d = idx >> 3, ck = idx & 7;
        vreg[i] = *(const bf16x8*)&vtb[(size_t)(h * DKH + d) * TT + kstart + ck * 8];
    }

#pragma unroll
    for (int it = 0; it < KSP / 64; ++it) {
        const int kc = kstart + it * 64;
        __syncthreads();
#pragma unroll
        for (int i = 0; i < 3; ++i) {
            const int idx = t + 256 * i;
            const int r = idx / 12, c = idx % 12;
            *(bf16x8*)&Ks[r][c * 8] = kreg[i];
            const int d = idx >> 3, ck = idx & 7;
            *(bf16x8*)&Vts[d][ck * 8] = vreg[i];
        }
        __syncthreads();

        if (it + 1 < KSP / 64) {
#pragma unroll
            for (int i = 0; i < 3; ++i) {
                const int idx = t + 256 * i;
                const int r = idx / 12, c = idx % 12;
                kreg[i] = *(const bf16x8*)&kb[(size_t)(kc + 64 + r) * DM + h * DKH + c * 8];
                const int d = idx >> 3, ck = idx & 7;
                vreg[i] = *(const bf16x8*)&vtb[(size_t)(h * DKH + d) * TT + kc + 64 + ck * 8];
            }
        }

        f32x4 Sa[4] = {fz, fz, fz, fz};
        __builtin_amdgcn_s_setprio(1);
#pragma unroll
        for (int nt = 0; nt < 4; ++nt)
#pragma unroll
            for (int ks = 0; ks < 3; ++ks) {
                const bf16x8 kf = *(const bf16x8*)&Ks[l15 + 16 * nt][quad * 8 + 32 * ks];
                Sa[nt] = __builtin_amdgcn_mfma_f32_16x16x32_bf16(qf[ks], kf, Sa[nt], 0, 0, 0);
            }
        __builtin_amdgcn_s_setprio(0);

#pragma unroll
        for (int r = 0; r < 4; ++r) {
            const float p0 = __builtin_amdgcn_exp2f(Sa[0][r]);
            const float p1 = __builtin_amdgcn_exp2f(Sa[1][r]);
            const float p2 = __builtin_amdgcn_exp2f(Sa[2][r]);
            const float p3 = __builtin_amdgcn_exp2f(Sa[3][r]);
            Ps[w][quad * 4 + r][l15]      = (__bf16)p0;
            Ps[w][quad * 4 + r][l15 + 16] = (__bf16)p1;
            Ps[w][quad * 4 + r][l15 + 32] = (__bf16)p2;
            Ps[w][quad * 4 + r][l15 + 48] = (__bf16)p3;
            if (MODE == 0) {
                float ps = p0 + p1 + p2 + p3;
                ps += __shfl_xor(ps, 1);
                ps += __shfl_xor(ps, 2);
                ps += __shfl_xor(ps, 4);
                ps += __shfl_xor(ps, 8);
                lrow[r] += ps;
            }
        }

        const bf16x8 pa0 = *(const bf16x8*)&Ps[w][l15][quad * 8];
        const bf16x8 pa1 = *(const bf16x8*)&Ps[w][l15][32 + quad * 8];

        __builtin_amdgcn_s_setprio(1);
#pragma unroll
        for (int nt = 0; nt < 6; ++nt) {
            const bf16x8 vf0 = *(const bf16x8*)&Vts[l15 + 16 * nt][quad * 8];
            const bf16x8 vf1 = *(const bf16x8*)&Vts[l15 + 16 * nt][32 + quad * 8];
            Oa[nt] = __builtin_amdgcn_mfma_f32_16x16x32_bf16(pa0, vf0, Oa[nt], 0, 0, 0);
            Oa[nt] = __builtin_amdgcn_mfma_f32_16x16x32_bf16(pa1, vf1, Oa[nt], 0, 0, 0);
        }
        if (MODE == 1) {
            const bf16x8 of0 = *(const bf16x8*)&Vts[96 + l15][quad * 8];
            const bf16x8 of1 = *(const bf16x8*)&Vts[96 + l15][32 + quad * 8];
            Lacc = __builtin_amdgcn_mfma_f32_16x16x32_bf16(pa0, of0, Lacc, 0, 0, 0);
            Lacc = __builtin_amdgcn_mfma_f32_16x16x32_bf16(pa1, of1, Lacc, 0, 0, 0);
        }
        __builtin_amdgcn_s_setprio(0);
    }

    if (MODE == 0) {
#pragma unroll
        for (int nt = 0; nt < 6; ++nt)
#pragma unroll
            for (int r = 0; r < 4; ++r) {
                const int row = q0 + 16 * w + quad * 4 + r;
                ob[(size_t)row * DM + h * DKH + 16 * nt + l15] = f2b(Oa[nt][r] / lrow[r]);
            }
    } else {
#pragma unroll
        for (int nt = 0; nt < 6; ++nt)
#pragma unroll
            for (int r = 0; r < 4; ++r) {
                const int row = q0 + 16 * w + quad * 4 + r;
                Opb[((size_t)p * TT + row) * DM + h * DKH + 16 * nt + l15] = f2b(Oa[nt][r]);
            }
        if (l15 == 0) {
#pragma unroll
            for (int r = 0; r < 4; ++r) {
                const int row = q0 + 16 * w + quad * 4 + r;
                Lp[((size_t)p * NH + h) * TT + row] = Lacc[r];
            }
        }
    }
}

// ---------------------------------------------------------------------------
// merge: 8 rows/block, bf16x8 vector loads.
// ---------------------------------------------------------------------------
__global__ __launch_bounds__(256) void attn_merge(const bf16* __restrict__ Opb,
                                                  const float* __restrict__ Lp,
                                                  bf16* __restrict__ ob) {
    __shared__ float Ls[8][NH];
    const int r0 = blockIdx.x * 8;
    const int t = threadIdx.x;
    if (t < 8 * NH) {
        const int rl = t >> 3, hh = t & 7;
        float L = 0.f;
#pragma unroll
        for (int p = 0; p < SP; ++p) L += Lp[((size_t)p * NH + hh) * TT + r0 + rl];
        Ls[rl][hh] = 1.0f / L;
    }
    __syncthreads();
    const int rl = t >> 5, lane = t & 31;
    const int row = r0 + rl;
#pragma unroll
    for (int j = 0; j < 3; ++j) {
        const int d0 = lane * 8 + j * 256;
        float acc[8];
#pragma unroll
        for (int e = 0; e < 8; ++e) acc[e] = 0.f;
#pragma unroll
        for (int p = 0; p < SP; ++p) {
            const bf16x8 vv = *(const bf16x8*)&Opb[((size_t)p * TT + row) * DM + d0];
#pragma unroll
            for (int e = 0; e < 8; ++e) acc[e] += (float)vv[e];
        }
        const float s = Ls[rl][d0 / DKH];
        bf16x8 o;
#pragma unroll
        for (int e = 0; e < 8; ++e) o[e] = (__bf16)(acc[e] * s);
        *(bf16x8*)&ob[(size_t)row * DM + d0] = o;
    }
}

__global__ __launch_bounds__(256) void add_ln(bf16* __restrict__ x,
                                              const bf16* __restrict__ r,
                                              const float* __restrict__ g,
                                              const float* __restrict__ be) {
    __shared__ float red[4];
    const int row = blockIdx.x;
    bf16* xr = x + (size_t)row * DM;
    const bf16* rr = r + (size_t)row * DM;
    const int t = threadIdx.x;

    float v0 = b2f(xr[t]) + b2f(rr[t]);
    float v1 = b2f(xr[t + 256]) + b2f(rr[t + 256]);
    float v2 = b2f(xr[t + 512]) + b2f(rr[t + 512]);
    float s = v0 + v1 + v2;
#pragma unroll
    for (int off = 32; off >= 1; off >>= 1) s += __shfl_xor(s, off);
    if ((t & 63) == 0) red[t >> 6] = s;
    __syncthreads();
    s = red[0] + red[1] + red[2] + red[3];
    const float mean = s * (1.f / 768.f);
    __syncthreads();

    const float d0 = v0 - mean, d1 = v1 - mean, d2 = v2 - mean;
    float ss = d0 * d0 + d1 * d1 + d2 * d2;
#pragma unroll
    for (int off = 32; off >= 1; off >>= 1) ss += __shfl_xor(ss, off);
    if ((t & 63) == 0) red[t >> 6] = ss;
    __syncthreads();
    ss = red[0] + red[1] + red[2] + red[3];
    const float inv = rsqrtf(ss * (1.f / 768.f) + LN_EPS);

    xr[t]       = f2b(d0 * inv * g[t]       + be[t]);
    xr[t + 256] = f2b(d1 * inv * g[t + 256] + be[t + 256]);
    xr[t + 512] = f2b(d2 * inv * g[t + 512] + be[t + 512]);
}

__global__ __launch_bounds__(256) void predict(const bf16* __restrict__ x,
                                               const float* __restrict__ ng,
                                               const float* __restrict__ nb,
                                               const float* __restrict__ Wp,
                                               const float* __restrict__ bp,
                                               float* __restrict__ out) {
    __shared__ float xs[BAG][DM];
    __shared__ float red[4][BAG];
    const int t = threadIdx.x;
    const int rel = blockIdx.x;
    const int wid = t >> 6, lane = t & 63;

    for (int rep = 0; rep < 2; ++rep) {
        const int b = wid + rep * 4;
        const bf16* row = x + (size_t)(294 * b + 1) * DM;
        float vals[12];
        float s = 0.f;
#pragma unroll
        for (int i = 0; i < 12; ++i) { vals[i] = b2f(row[lane + i * 64]); s += vals[i]; }
#pragma unroll
        for (int off = 32; off >= 1; off >>= 1) s += __shfl_xor(s, off);
        const float mean = s * (1.f / 768.f);
        float ss = 0.f;
#pragma unroll
        for (int i = 0; i < 12; ++i) { const float d = vals[i] - mean; ss += d * d; }
#pragma unroll
        for (int off = 32; off >= 1; off >>= 1) ss += __shfl_xor(ss, off);
        const float inv = rsqrtf(ss * (1.f / 768.f) + LN_EPS);
#pragma unroll
        for (int i = 0; i < 12; ++i) {
            const int d = lane + i * 64;
            xs[b][d] = (vals[i] - mean) * inv * ng[d] + nb[d];
        }
    }
    __syncthreads();

    float pb[BAG];
#pragma unroll
    for (int b = 0; b < BAG; ++b) pb[b] = 0.f;
    for (int k = t; k < DM; k += 256) {
        const float wv = Wp[(size_t)k * NREL + rel];
#pragma unroll
        for (int b = 0; b < BAG; ++b) pb[b] += xs[b][k] * wv;
    }
#pragma unroll
    for (int b = 0; b < BAG; ++b)
#pragma unroll
        for (int off = 32; off >= 1; off >>= 1) pb[b] += __shfl_xor(pb[b], off);
    if (lane == 0)
#pragma unroll
        for (int b = 0; b < BAG; ++b) red[wid][b] = pb[b];
    __syncthreads();
    if (t == 0) {
        float mx = -3.0e38f;
        for (int b = 0; b < BAG; ++b) {
            const float v = red[0][b] + red[1][b] + red[2][b] + red[3][b] + bp[rel];
            out[NREL + b * NREL + rel] = v;
            mx = fmaxf(mx, v);
        }
        out[rel] = mx;
    }
}

// ---------------------------------------------------------------------------
// host. ws layout (bytes), high-water 48,635,904:
//   htb 0 | u2 73728 (48x1536 fused u|v) | x 221184 | Bq 3760128
//   Bk 7299072 | Bv 10838016 | Vt 15556608 | slab 19095552 | Opb 26959872
//   (SP=6 bf16, 21.2 MB) | Lp 48193536
// ---------------------------------------------------------------------------
extern "C" void kernel_launch(void* const* d_in, const int* in_sizes, int n_in,
                              void* d_out, int out_size, void* d_ws, size_t ws_size,
                              hipStream_t stream) {
    const float* emb  = (const float*)d_in[0];
    const int* spans  = (const int*)d_in[1];
    const float* Wu = (const float*)d_in[2];  const float* bu = (const float*)d_in[3];
    const float* Wv = (const float*)d_in[4];  const float* bv = (const float*)d_in[5];
    const float* Wl = (const float*)d_in[6];  const float* bl = (const float*)d_in[7];
    const float* Wq = (const float*)d_in[8];  const float* bq = (const float*)d_in[9];
    const float* Wk = (const float*)d_in[10]; const float* bk = (const float*)d_in[11];
    const float* Wvm = (const float*)d_in[12]; const float* bvm = (const float*)d_in[13];
    const float* Wo = (const float*)d_in[14]; const float* bo = (const float*)d_in[15];
    const float* F1 = (const float*)d_in[16]; const float* f1 = (const float*)d_in[17];
    const float* F2 = (const float*)d_in[18]; const float* f2 = (const float*)d_in[19];
    const float* g1 = (const float*)d_in[20]; const float* be1 = (const float*)d_in[21];
    const float* g2 = (const float*)d_in[22]; const float* be2 = (const float*)d_in[23];
    const float* ng = (const float*)d_in[24]; const float* nb = (const float*)d_in[25];
    const float* Wp = (const float*)d_in[26]; const float* bp = (const float*)d_in[27];

    char* wsb = (char*)d_ws;
    bf16* htb = (bf16*)(wsb + 0);
    bf16* u2  = (bf16*)(wsb + 73728);     // full path: 48x1536 fused u|v
    bf16* ub  = (bf16*)(wsb + 73728);     // fallback: 48x768
    bf16* vbn = (bf16*)(wsb + 147456);    // fallback: 48x768
    bf16* x   = (bf16*)(wsb + 221184);
    bf16* Bq  = (bf16*)(wsb + 3760128);
    bf16* Bk  = (bf16*)(wsb + 7299072);
    bf16* Bv  = (bf16*)(wsb + 10838016);
    bf16* Vt  = (bf16*)(wsb + 15556608);
    bf16* slab = (bf16*)(wsb + 19095552);
    bf16* Opb = (bf16*)(wsb + 26959872);
    float* Lp = (float*)(wsb + 48193536);

    const size_t FULL_END = 48635904;
    const bool use_full = ws_size >= FULL_END;

    span_pool<<<dim3(NNODE, 6), 128, 0, stream>>>(emb, spans, htb);

    if (use_full) {
        prep_wt3<<<dim3(12, 12, 3), 256, 0, stream>>>(Wu, Wv, Wl, slab);
        // fused u|v GEMM: Bt = [Wu^T ; Wv^T] contiguous in slab, N=1536
        gemm_bt256<0, 1><<<dim3(24, 1), 256, 0, stream>>>(htb, slab, bu, bv, u2,
                                                          NNODE, 2 * DM, DM);
        // rel GEMM with fused relu(u_i+v_j) A-staging
        gemm_rel<<<dim3(12, TT / 64), 256, 0, stream>>>(u2, slab + 1179648, bl, x);

        for (int l = 0; l < NLAYER; ++l) {
            const size_t wo = (size_t)l * DM * DM;
            const size_t f1o = (size_t)l * DM * DFF;
            prep6<<<dim3(16, 16, 6), 256, 0, stream>>>(Wq + wo, Wk + wo, Wvm + wo,
                                                       Wo + wo, F1 + f1o, F2 + f1o, slab);
            gemm_qkv256<<<dim3(36, TT / 64), 256, 0, stream>>>(x, slab, bq + l * DM, bk + l * DM,
                                                               bvm + l * DM, Bq, Bk, Vt);
            attn_mfma<1, KSPAN><<<dim3(36 * NH * SP), 256, 0, stream>>>(Bq, Bk, Vt, Bq, Opb, Lp);
            attn_merge<<<TT / 8, 256, 0, stream>>>(Opb, Lp, Bq);
            gemm_bt256<0, 0><<<dim3(12, TT / 64), 256, 0, stream>>>(Bq, slab + 1769472, bo + l * DM,
                                                                    bo + l * DM, Bk, TT, DM, DM);
            add_ln<<<TT, 256, 0, stream>>>(x, Bk, g1 + l * DM, be1 + l * DM);
            gemm_bt256<1, 0><<<dim3(16, TT / 64), 256, 0, stream>>>(x, slab + 2359296, f1 + l * DFF,
                                                                    f1 + l * DFF, Bv, TT, DFF, DM);
            gemm_bt256<0, 0><<<dim3(12, TT / 64), 256, 0, stream>>>(Bv, slab + 3145728, f2 + l * DM,
                                                                    f2 + l * DM, Bk, TT, DM, DFF);
            add_ln<<<TT, 256, 0, stream>>>(x, Bk, g2 + l * DM, be2 + l * DM);
        }
    } else {
        gemm_mfma<0><<<dim3(12, 2), 128, 0, stream>>>(htb, Wu, bu, ub, NNODE, DM, DM);
        gemm_mfma<0><<<dim3(12, 2), 128, 0, stream>>>(htb, Wv, bv, vbn, NNODE, DM, DM);
        build_relA<<<TT, 256, 0, stream>>>(ub, vbn, DM, Bq);
        gemm_mfma<1><<<dim3(12, TT / 32), 128, 0, stream>>>(Bq, Wl, bl, x, TT, DM, DM);

        for (int l = 0; l < NLAYER; ++l) {
            const size_t wo = (size_t)l * DM * DM;
            const size_t f1o = (size_t)l * DM * DFF;
            gemm_mfma<0><<<dim3(12, TT / 32), 128, 0, stream>>>(x, Wq + wo, bq + l * DM, Bq, TT, DM, DM);
            gemm_mfma<0><<<dim3(12, TT / 32), 128, 0, stream>>>(x, Wk + wo, bk + l * DM, Bk, TT, DM, DM);
            gemm_mfma<0><<<dim3(12, TT / 32), 128, 0, stream>>>(x, Wvm + wo, bvm + l * DM, Bv, TT, DM, DM);
            transpose_v<<<dim3(DM / 64, TT / 64), 256, 0, stream>>>(Bv, Vt);
            attn_mfma<0, TT><<<dim3(36 * NH), 256, 0, stream>>>(Bq, Bk, Vt, Bq, Opb, Lp);
            gemm_mfma<0><<<dim3(12, TT / 32), 128, 0, stream>>>(Bq, Wo + wo, bo + l * DM, Bk, TT, DM, DM);
            add_ln<<<TT, 256, 0, stream>>>(x, Bk, g1 + l * DM, be1 + l * DM);
            gemm_mfma<1><<<dim3(16, TT / 32), 128, 0, stream>>>(x, F1 + f1o, f1 + l * DFF, Bv, TT, DFF, DM);
            gemm_mfma<0><<<dim3(12, TT / 32), 128, 0, stream>>>(Bv, F2 + f1o, f2 + l * DM, Bk, TT, DM, DFF);
            add_ln<<<TT, 256, 0, stream>>>(x, Bk, g2 + l * DM, be2 + l * DM);
        }
    }

    predict<<<NREL, 256, 0, stream>>>(x, ng, nb, Wp, bp, (float*)d_out);
}